// Round 10
// baseline (224.016 us; speedup 1.0000x reference)
//
#include <hip/hip_runtime.h>
#include <hip/hip_bf16.h>
#include <cmath>

// Problem constants (fixed by reference)
constexpr int Bb = 2;
constexpr int Ls = 2048;
constexpr int Dd = 1024;
constexpr int Hh = 16;
constexpr int DHh = 64;
constexpr int Rr = 32;
constexpr int BL = Bb * Ls;          // 4096
constexpr float LORA_SCALE = 2.0f;   // 64/32
constexpr float LN_EPS = 1e-5f;
constexpr float ATTN_SCALE = 0.125f; // 1/sqrt(64)
constexpr float LOG2E = 1.4426950408889634f;
constexpr float QSCL = ATTN_SCALE * LOG2E;  // folded into qt

typedef __attribute__((ext_vector_type(8))) short bf16x8;
typedef __attribute__((ext_vector_type(4))) float f32x4;

__device__ __forceinline__ unsigned short f2bf(float f) {
    __hip_bfloat16 b = __float2bfloat16(f);
    return *reinterpret_cast<unsigned short*>(&b);
}
__device__ __forceinline__ float bf2f(unsigned short u) {
    unsigned int x = ((unsigned int)u) << 16;
    return __uint_as_float(x);
}
__device__ __forceinline__ void async_copy16(const void* g, void* l) {
    __builtin_amdgcn_global_load_lds(
        (__attribute__((address_space(1))) void*)(void*)(size_t)g,
        (__attribute__((address_space(3))) void*)l, 16, 0, 0);
}

// ---------------- block-wide sum over 256 threads ----------------
__device__ __forceinline__ float block_sum_256(float v, float* red) {
#pragma unroll
    for (int o = 32; o > 0; o >>= 1) v += __shfl_down(v, o, 64);
    const int lane = threadIdx.x & 63;
    const int wid = threadIdx.x >> 6;
    if (lane == 0) red[wid] = v;
    __syncthreads();
    float s = red[0] + red[1] + red[2] + red[3];
    __syncthreads();
    return s;
}

// ---------------- 0. fused prep: merge-LoRA-wqkv | cast w_out | rope table ----
__global__ __launch_bounds__(256) void prep_kernel(const float* __restrict__ w,
                                                   const float* __restrict__ qa,
                                                   const float* __restrict__ qb,
                                                   const float* __restrict__ va,
                                                   const float* __restrict__ vb,
                                                   const float* __restrict__ wout,
                                                   unsigned short* __restrict__ wqkvb,
                                                   unsigned short* __restrict__ woutb,
                                                   float* __restrict__ ropec,
                                                   float* __restrict__ ropes) {
    const int blk = blockIdx.x;
    const int tid = threadIdx.x;
    if (blk < 3 * Dd) {
        const int e = blk;
        const int d0 = tid * 4;
        __shared__ float br[Rr];
        const bool isq = (e < Dd);
        const bool isv = (e >= 2 * Dd);
        const float* bsrc = isq ? (qb + (size_t)e * Rr)
                                : (isv ? (vb + (size_t)(e - 2 * Dd) * Rr) : nullptr);
        const float* asrc = isq ? qa : va;
        if (bsrc && tid < Rr) br[tid] = bsrc[tid];
        __syncthreads();
        float acc[4] = {0.f, 0.f, 0.f, 0.f};
        if (bsrc) {
#pragma unroll 8
            for (int r = 0; r < Rr; ++r) {
                float4 av = *(const float4*)(asrc + (size_t)r * Dd + d0);
                acc[0] += br[r] * av.x; acc[1] += br[r] * av.y;
                acc[2] += br[r] * av.z; acc[3] += br[r] * av.w;
            }
        }
        float4 wv = *(const float4*)(w + (size_t)e * Dd + d0);
        ushort4 o;
        o.x = f2bf(wv.x + LORA_SCALE * acc[0]);
        o.y = f2bf(wv.y + LORA_SCALE * acc[1]);
        o.z = f2bf(wv.z + LORA_SCALE * acc[2]);
        o.w = f2bf(wv.w + LORA_SCALE * acc[3]);
        *(ushort4*)(wqkvb + (size_t)e * Dd + d0) = o;
    } else if (blk < 4 * Dd) {
        int i = ((blk - 3 * Dd) * 256 + tid) * 4;
        float4 v = *(const float4*)(wout + i);
        ushort4 o;
        o.x = f2bf(v.x); o.y = f2bf(v.y); o.z = f2bf(v.z); o.w = f2bf(v.w);
        *(ushort4*)(woutb + i) = o;
    } else {
        int i = (blk - 4 * Dd) * 256 + tid;    // over Ls*32
        int l = i >> 5;
        int f = i & 31;
        float invf = powf(10000.0f, -(float)f * (1.0f / 32.0f));
        float ang = (float)l * invf;
        float s, c;
        sincosf(ang, &s, &c);
        ropec[i] = c;
        ropes[i] = s;
    }
}

// ---------------- 1. LayerNorm(x) -> h (bf16) ----------------
__global__ __launch_bounds__(256) void ln_x_kernel(const float* __restrict__ x,
                                                   const float* __restrict__ w,
                                                   const float* __restrict__ b,
                                                   unsigned short* __restrict__ hb) {
    const int row = blockIdx.x;
    const int tid = threadIdx.x;
    __shared__ float red[4];
    float4 xv = *(const float4*)(x + (size_t)row * Dd + tid * 4);
    float v[4] = {xv.x, xv.y, xv.z, xv.w};
    float s = v[0] + v[1] + v[2] + v[3];
    float mean = block_sum_256(s, red) * (1.0f / Dd);
    float sq = 0.f;
#pragma unroll
    for (int j = 0; j < 4; ++j) {
        v[j] -= mean;
        sq += v[j] * v[j];
    }
    float var = block_sum_256(sq, red) * (1.0f / Dd);
    float rs = rsqrtf(var + LN_EPS);
    ushort4 o;
    unsigned short* op = (unsigned short*)&o;
#pragma unroll
    for (int j = 0; j < 4; ++j) {
        int d = tid * 4 + j;
        op[j] = f2bf(v[j] * rs * w[d] + b[d]);
    }
    *(ushort4*)(hb + (size_t)row * Dd + tid * 4) = o;
}

// ---------------- 2. MFMA GEMM: C[M,N] = A[M,K] * B[N,K]^T ----------------
template <bool OUT_BF16>
__global__ __launch_bounds__(256) void gemm_bt_mfma(const unsigned short* __restrict__ A,
                                                    const unsigned short* __restrict__ B,
                                                    void* __restrict__ Cv,
                                                    int M, int N, int K) {
    __shared__ short As[128 * 64];
    __shared__ short Bs[128 * 64];
    const int tid = threadIdx.x;
    const int w = tid >> 6, lane = tid & 63, quad = lane >> 4, l15 = lane & 15;
    const int m0 = blockIdx.y * 128, n0 = blockIdx.x * 128;
    const int wm = (w & 1) * 64, wn = (w >> 1) * 64;
    f32x4 acc[4][4];
#pragma unroll
    for (int i = 0; i < 4; ++i)
#pragma unroll
        for (int j = 0; j < 4; ++j) acc[i][j] = f32x4{0.f, 0.f, 0.f, 0.f};

    for (int k0 = 0; k0 < K; k0 += 64) {
#pragma unroll
        for (int j = 0; j < 4; ++j) {
            int c = tid + j * 256;
            int row = c >> 3;
            int jg = (c & 7) ^ (row & 7);
            async_copy16(A + (size_t)(m0 + row) * K + k0 + jg * 8, As + c * 8);
        }
#pragma unroll
        for (int j = 0; j < 4; ++j) {
            int c = tid + j * 256;
            int row = c >> 3;
            int jg = (c & 7) ^ (row & 7);
            async_copy16(B + (size_t)(n0 + row) * K + k0 + jg * 8, Bs + c * 8);
        }
        __syncthreads();
#pragma unroll
        for (int ks = 0; ks < 2; ++ks) {
            bf16x8 a[4], b[4];
#pragma unroll
            for (int mi = 0; mi < 4; ++mi) {
                int row = wm + mi * 16 + l15;
                int ch = (ks * 4 + quad) ^ (row & 7);
                a[mi] = *(const bf16x8*)&As[row * 64 + ch * 8];
            }
#pragma unroll
            for (int ni = 0; ni < 4; ++ni) {
                int row = wn + ni * 16 + l15;
                int ch = (ks * 4 + quad) ^ (row & 7);
                b[ni] = *(const bf16x8*)&Bs[row * 64 + ch * 8];
            }
#pragma unroll
            for (int mi = 0; mi < 4; ++mi)
#pragma unroll
                for (int ni = 0; ni < 4; ++ni)
                    acc[mi][ni] = __builtin_amdgcn_mfma_f32_16x16x32_bf16(a[mi], b[ni], acc[mi][ni], 0, 0, 0);
        }
        __syncthreads();
    }
    if (OUT_BF16) {
        unsigned short* C = (unsigned short*)Cv;
#pragma unroll
        for (int mi = 0; mi < 4; ++mi)
#pragma unroll
            for (int ni = 0; ni < 4; ++ni)
#pragma unroll
                for (int r = 0; r < 4; ++r)
                    C[(size_t)(m0 + wm + mi * 16 + quad * 4 + r) * N + n0 + wn + ni * 16 + l15] =
                        f2bf(acc[mi][ni][r]);
    } else {
        float* C = (float*)Cv;
#pragma unroll
        for (int mi = 0; mi < 4; ++mi)
#pragma unroll
            for (int ni = 0; ni < 4; ++ni)
#pragma unroll
                for (int r = 0; r < 4; ++r)
                    C[(size_t)(m0 + wm + mi * 16 + quad * 4 + r) * N + n0 + wn + ni * 16 + l15] =
                        acc[mi][ni][r];
    }
}

// ---------------- 3. Q/K finalize: LN + RoPE -> bf16 [B,H,L,DH] ----------------
__global__ __launch_bounds__(256) void qkv_final_kernel(const unsigned short* __restrict__ qkvb,
                                                        const float* __restrict__ qlnw,
                                                        const float* __restrict__ klnw,
                                                        const float* __restrict__ ropec,
                                                        const float* __restrict__ ropes,
                                                        unsigned short* __restrict__ qt,
                                                        unsigned short* __restrict__ kt) {
    const int row = blockIdx.x;
    const int b = row >> 11;
    const int l = row & (Ls - 1);
    const int tid = threadIdx.x;
    __shared__ float yrow[Dd];
    __shared__ float red[4];

    const int d0 = tid * 4;
    const int hh = d0 >> 6;
    const int dh0 = d0 & 63;
    float cs4[4], sn4[4];
#pragma unroll
    for (int j = 0; j < 4; ++j) {
        int f = (dh0 + j) & 31;
        cs4[j] = ropec[l * 32 + f];
        sn4[j] = ropes[l * 32 + f];
    }
    const size_t dst_off = (((size_t)(b * Hh + hh)) * Ls + l) * DHh + dh0;

    // ---- Q: LN + RoPE + prescale ----
    {
        ushort4 qv = *(const ushort4*)(qkvb + (size_t)row * (3 * Dd) + d0);
        float v[4] = {bf2f(qv.x), bf2f(qv.y), bf2f(qv.z), bf2f(qv.w)};
        float s = v[0] + v[1] + v[2] + v[3];
        float mean = block_sum_256(s, red) * (1.0f / Dd);
        float sq = 0.f;
#pragma unroll
        for (int j = 0; j < 4; ++j) {
            v[j] -= mean;
            sq += v[j] * v[j];
        }
        float var = block_sum_256(sq, red) * (1.0f / Dd);
        float rs = rsqrtf(var + LN_EPS);
#pragma unroll
        for (int j = 0; j < 4; ++j) yrow[d0 + j] = v[j] * rs * qlnw[d0 + j];
        __syncthreads();
        ushort4 pk;
        unsigned short* pp = (unsigned short*)&pk;
#pragma unroll
        for (int j = 0; j < 4; ++j) {
            int d = d0 + j;
            int dh = dh0 + j;
            float rot = (dh < 32) ? -yrow[d + 32] : yrow[d - 32];
            pp[j] = f2bf((yrow[d] * cs4[j] + rot * sn4[j]) * QSCL);
        }
        *(ushort4*)(qt + dst_off) = pk;
    }
    __syncthreads();  // yrow reuse

    // ---- K: LN + RoPE ----
    {
        ushort4 kv = *(const ushort4*)(qkvb + (size_t)row * (3 * Dd) + Dd + d0);
        float v[4] = {bf2f(kv.x), bf2f(kv.y), bf2f(kv.z), bf2f(kv.w)};
        float s = v[0] + v[1] + v[2] + v[3];
        float mean = block_sum_256(s, red) * (1.0f / Dd);
        float sq = 0.f;
#pragma unroll
        for (int j = 0; j < 4; ++j) {
            v[j] -= mean;
            sq += v[j] * v[j];
        }
        float var = block_sum_256(sq, red) * (1.0f / Dd);
        float rs = rsqrtf(var + LN_EPS);
#pragma unroll
        for (int j = 0; j < 4; ++j) yrow[d0 + j] = v[j] * rs * klnw[d0 + j];
        __syncthreads();
        ushort4 pk;
        unsigned short* pp = (unsigned short*)&pk;
#pragma unroll
        for (int j = 0; j < 4; ++j) {
            int d = d0 + j;
            int dh = dh0 + j;
            float rot = (dh < 32) ? -yrow[d + 32] : yrow[d - 32];
            pp[j] = f2bf(yrow[d] * cs4[j] + rot * sn4[j]);
        }
        *(ushort4*)(kt + dst_off) = pk;
    }
}

// ---------------- 4. V transpose: qkv bf16 v-section -> vtt bf16 [B,H,DH,L] ----
__global__ __launch_bounds__(256) void transpose_v_kernel(const unsigned short* __restrict__ qkvb,
                                                          unsigned short* __restrict__ vtt) {
    const int l0 = blockIdx.x * 64;
    const int h = blockIdx.y;
    const int b = blockIdx.z;
    const int tid = threadIdx.x;
    __shared__ short t[64][72];
    const unsigned short* src = qkvb + (size_t)b * Ls * (3 * Dd) + 2 * Dd + h * 64;
#pragma unroll
    for (int j = 0; j < 2; ++j) {
        int g = tid + j * 256;
        int row = g >> 3;
        int c0 = (g & 7) * 8;
        uint4 vv = *(const uint4*)(src + (size_t)(l0 + row) * (3 * Dd) + c0);
        *(uint4*)&t[row][c0] = vv;
    }
    __syncthreads();
    unsigned short* dst = vtt + ((size_t)(b * Hh + h) * DHh) * Ls;
#pragma unroll
    for (int j = 0; j < 2; ++j) {
        int g = tid + j * 256;
        int dh = g >> 3;
        int lc = (g & 7) * 8;
        ushort4 o0, o1;
        unsigned short* p0 = (unsigned short*)&o0;
        unsigned short* p1 = (unsigned short*)&o1;
#pragma unroll
        for (int i = 0; i < 4; ++i) p0[i] = (unsigned short)t[lc + i][dh];
#pragma unroll
        for (int i = 0; i < 4; ++i) p1[i] = (unsigned short)t[lc + 4 + i][dh];
        *(ushort4*)(dst + (size_t)dh * Ls + l0 + lc) = o0;
        *(ushort4*)(dst + (size_t)dh * Ls + l0 + lc + 4) = o1;
    }
}

// ---------------- 5. MFMA flash attention v3 ---------------------------------
// m97-style single-buffer staging (stage; barrier; compute; barrier) — LDS
// 26.4 KB -> full 4 blocks/CU residency (grid 1024, single round, 16 waves/CU).
// Q fragments live in registers (one-time global load, no Qs buffer).
constexpr int PSP = 76;  // Ps pitch

__global__ __launch_bounds__(256) void attn_kernel(const unsigned short* __restrict__ qt,
                                                   const unsigned short* __restrict__ kt,
                                                   const unsigned short* __restrict__ vtt,
                                                   const int* __restrict__ seq_id,
                                                   unsigned short* __restrict__ ctxb) {
    const int id = blockIdx.x;            // 0..1023
    const int c8 = id & 7;
    const int x = (id >> 3) & 31;
    const int g8 = id >> 8;               // 0..3
    const int v = c8 + 8 * g8;            // h + 16*b
    const int b = v >> 4;
    const int h = v & 15;
    const int q0 = x * 64;

    const size_t base = ((size_t)(b * Hh + h)) * Ls * DHh;
    const size_t base_v = ((size_t)(b * Hh + h)) * DHh * Ls;
    const int* sid = seq_id + (size_t)b * Ls;

    __shared__ short Ks[64 * 64];
    __shared__ short Vs[64 * 64];
    __shared__ short Ps[4][16 * PSP];
    __shared__ int sq_s[64];

    const int tid = threadIdx.x;
    const int w = tid >> 6;
    const int lane = tid & 63;
    const int quad = lane >> 4;
    const int l15 = lane & 15;

    if (tid < 64) sq_s[tid] = sid[q0 + tid];
    const int qmin = sid[q0];
    const int qmax = sid[q0 + 63];

    // Q fragments direct from global (one-time; compiler inserts waitcnt)
    const int qrow = q0 + w * 16 + l15;
    bf16x8 a0 = *(const bf16x8*)(qt + base + (size_t)qrow * DHh + quad * 8);
    bf16x8 a1 = *(const bf16x8*)(qt + base + (size_t)qrow * DHh + 32 + quad * 8);

    // contiguous needed-tile range via ballot (tiles 0..31)
    bool need = false;
    if (lane < 32) {
        int kmn = sid[lane * 64];
        int kmx = sid[lane * 64 + 63];
        need = (kmn <= qmax) && (kmx >= qmin);
    }
    unsigned long long bmask = __ballot(need);
    const int t0 = __builtin_ctzll(bmask);
    const int t1 = 64 - __builtin_clzll(bmask);

    float lsum[4] = {0.f, 0.f, 0.f, 0.f};
    f32x4 O[4];
#pragma unroll
    for (int r = 0; r < 4; ++r) O[r] = f32x4{0.f, 0.f, 0.f, 0.f};

    for (int t = t0; t < t1; ++t) {
        const int k0 = t * 64;
        __syncthreads();   // previous tile's readers done (also covers sq_s init)
        // stage K (row-major) + V (dh-major) async, xor-swizzled chunks
#pragma unroll
        for (int j = 0; j < 2; ++j) {
            int cc = tid + j * 256;
            int row = cc >> 3;
            int jg = (cc & 7) ^ (row & 7);
            async_copy16(kt + base + (size_t)(k0 + row) * DHh + jg * 8, &Ks[cc * 8]);
            async_copy16(vtt + base_v + (size_t)row * Ls + k0 + jg * 8, &Vs[cc * 8]);
        }
        __syncthreads();   // drain (vmcnt(0) before barrier)

        // ---- S = Q K^T : 16 q rows x 64 keys per wave (log2 domain) ----
        f32x4 s[4];
#pragma unroll
        for (int kg = 0; kg < 4; ++kg) {
            int krow = kg * 16 + l15;
            bf16x8 b0 = *(const bf16x8*)&Ks[krow * 64 + ((0 + quad) ^ (krow & 7)) * 8];
            bf16x8 b1 = *(const bf16x8*)&Ks[krow * 64 + ((4 + quad) ^ (krow & 7)) * 8];
            f32x4 acc = {0.f, 0.f, 0.f, 0.f};
            acc = __builtin_amdgcn_mfma_f32_16x16x32_bf16(a0, b0, acc, 0, 0, 0);
            acc = __builtin_amdgcn_mfma_f32_16x16x32_bf16(a1, b1, acc, 0, 0, 0);
            s[kg] = acc;
        }
        // mask only boundary tiles
        const int kmn = sid[k0];
        const int kmx = sid[k0 + 63];
        const bool nomask = (kmn == kmx) && (qmin == qmax) && (kmn == qmin);
        if (!nomask) {
            int sqv[4];
#pragma unroll
            for (int r = 0; r < 4; ++r) sqv[r] = sq_s[w * 16 + quad * 4 + r];
#pragma unroll
            for (int kg = 0; kg < 4; ++kg) {
                int skv = sid[k0 + kg * 16 + l15];
#pragma unroll
                for (int r = 0; r < 4; ++r)
                    if (sqv[r] != skv) s[kg][r] = -3.0e38f;
            }
        }
        // p = exp2(s); per-lane l partials; P -> per-wave LDS (no barrier needed)
#pragma unroll
        for (int kg = 0; kg < 4; ++kg)
#pragma unroll
            for (int r = 0; r < 4; ++r)
                s[kg][r] = __builtin_amdgcn_exp2f(s[kg][r]);
#pragma unroll
        for (int r = 0; r < 4; ++r)
            lsum[r] += s[0][r] + s[1][r] + s[2][r] + s[3][r];
#pragma unroll
        for (int kg = 0; kg < 4; ++kg)
#pragma unroll
            for (int r = 0; r < 4; ++r)
                Ps[w][(quad * 4 + r) * PSP + kg * 16 + l15] = (short)f2bf(s[kg][r]);
        // ---- O += P V ----
        bf16x8 pa0 = *(const bf16x8*)&Ps[w][l15 * PSP + quad * 8];
        bf16x8 pa1 = *(const bf16x8*)&Ps[w][l15 * PSP + 32 + quad * 8];
#pragma unroll
        for (int ng = 0; ng < 4; ++ng) {
            int vrow = ng * 16 + l15;   // dh
            bf16x8 vb0 = *(const bf16x8*)&Vs[vrow * 64 + ((0 + quad) ^ (vrow & 7)) * 8];
            bf16x8 vb1 = *(const bf16x8*)&Vs[vrow * 64 + ((4 + quad) ^ (vrow & 7)) * 8];
            O[ng] = __builtin_amdgcn_mfma_f32_16x16x32_bf16(pa0, vb0, O[ng], 0, 0, 0);
            O[ng] = __builtin_amdgcn_mfma_f32_16x16x32_bf16(pa1, vb1, O[ng], 0, 0, 0);
        }
    }

    // deferred l reduction over the 16 key-lanes, then normalize
#pragma unroll
    for (int off = 1; off < 16; off <<= 1)
#pragma unroll
        for (int r = 0; r < 4; ++r)
            lsum[r] += __shfl_xor(lsum[r], off, 64);
    float inv_l[4];
#pragma unroll
    for (int r = 0; r < 4; ++r) inv_l[r] = 1.0f / lsum[r];
#pragma unroll
    for (int ng = 0; ng < 4; ++ng)
#pragma unroll
        for (int r = 0; r < 4; ++r) {
            int q = q0 + w * 16 + quad * 4 + r;
            ctxb[((size_t)b * Ls + q) * Dd + h * DHh + ng * 16 + l15] = f2bf(O[ng][r] * inv_l[r]);
        }
}

// ---------------- launcher ----------------
extern "C" void kernel_launch(void* const* d_in, const int* in_sizes, int n_in,
                              void* d_out, int out_size, void* d_ws, size_t ws_size,
                              hipStream_t stream) {
    const float* x = (const float*)d_in[0];
    const int* seq_id = (const int*)d_in[1];
    const float* ln_w = (const float*)d_in[2];
    const float* ln_b = (const float*)d_in[3];
    const float* w_qkv = (const float*)d_in[4];
    const float* q_lora_a = (const float*)d_in[5];
    const float* q_lora_b = (const float*)d_in[6];
    const float* v_lora_a = (const float*)d_in[7];
    const float* v_lora_b = (const float*)d_in[8];
    const float* q_ln_w = (const float*)d_in[9];
    const float* k_ln_w = (const float*)d_in[10];
    const float* w_out = (const float*)d_in[11];
    float* out = (float*)d_out;

    const size_t SZ = (size_t)BL * Dd;        // 4M elements
    float* p = (float*)d_ws;
    float* ropec = p;          p += (size_t)Ls * 32;
    float* ropes = p;          p += (size_t)Ls * 32;
    unsigned short* ub = (unsigned short*)p;
    unsigned short* qkvb = ub; ub += 3 * SZ;  // bf16 [BL, 3D]
    unsigned short* hb = ub;   ub += SZ;      // bf16 [BL, D]
    unsigned short* qt = ub;   ub += SZ;      // bf16 [B,H,L,DH] (prescaled)
    unsigned short* kt = ub;   ub += SZ;
    unsigned short* vtt = ub;  ub += SZ;      // bf16 [B,H,DH,L]
    unsigned short* ctxb = ub; ub += SZ;      // bf16 [BL, D]
    unsigned short* wqkvb = ub; ub += (size_t)3 * Dd * Dd;
    unsigned short* woutb = ub; ub += (size_t)Dd * Dd;

    prep_kernel<<<4 * Dd + 256, 256, 0, stream>>>(w_qkv, q_lora_a, q_lora_b,
                                                  v_lora_a, v_lora_b, w_out,
                                                  wqkvb, woutb, ropec, ropes);
    ln_x_kernel<<<BL, 256, 0, stream>>>(x, ln_w, ln_b, hb);
    {
        dim3 g(3 * Dd / 128, BL / 128);
        gemm_bt_mfma<true><<<g, 256, 0, stream>>>(hb, wqkvb, qkvb, BL, 3 * Dd, Dd);
    }
    qkv_final_kernel<<<BL, 256, 0, stream>>>(qkvb, q_ln_w, k_ln_w,
                                             ropec, ropes, qt, kt);
    {
        dim3 g(Ls / 64, Hh, Bb);
        transpose_v_kernel<<<g, 256, 0, stream>>>(qkvb, vtt);
    }
    attn_kernel<<<1024, 256, 0, stream>>>(qt, kt, vtt, seq_id, ctxb);
    {
        dim3 g(Dd / 128, BL / 128);
        gemm_bt_mfma<false><<<g, 256, 0, stream>>>(ctxb, woutb, out, BL, Dd, Dd);
    }
}

// Round 11
// 222.595 us; speedup vs baseline: 1.0064x; 1.0064x over previous
//
#include <hip/hip_runtime.h>
#include <hip/hip_bf16.h>
#include <cmath>

// Problem constants (fixed by reference)
constexpr int Bb = 2;
constexpr int Ls = 2048;
constexpr int Dd = 1024;
constexpr int Hh = 16;
constexpr int DHh = 64;
constexpr int Rr = 32;
constexpr int BL = Bb * Ls;          // 4096
constexpr float LORA_SCALE = 2.0f;   // 64/32
constexpr float LN_EPS = 1e-5f;
constexpr float ATTN_SCALE = 0.125f; // 1/sqrt(64)
constexpr float LOG2E = 1.4426950408889634f;
constexpr float QSCL = ATTN_SCALE * LOG2E;  // folded into qt

typedef __attribute__((ext_vector_type(8))) short bf16x8;
typedef __attribute__((ext_vector_type(4))) float f32x4;

__device__ __forceinline__ unsigned short f2bf(float f) {
    __hip_bfloat16 b = __float2bfloat16(f);
    return *reinterpret_cast<unsigned short*>(&b);
}
__device__ __forceinline__ float bf2f(unsigned short u) {
    unsigned int x = ((unsigned int)u) << 16;
    return __uint_as_float(x);
}
__device__ __forceinline__ void async_copy16(const void* g, void* l) {
    __builtin_amdgcn_global_load_lds(
        (__attribute__((address_space(1))) void*)(void*)(size_t)g,
        (__attribute__((address_space(3))) void*)l, 16, 0, 0);
}

// ---------------- block-wide sum over 256 threads ----------------
__device__ __forceinline__ float block_sum_256(float v, float* red) {
#pragma unroll
    for (int o = 32; o > 0; o >>= 1) v += __shfl_down(v, o, 64);
    const int lane = threadIdx.x & 63;
    const int wid = threadIdx.x >> 6;
    if (lane == 0) red[wid] = v;
    __syncthreads();
    float s = red[0] + red[1] + red[2] + red[3];
    __syncthreads();
    return s;
}

// ---------------- 0. fused prep: merge-LoRA-wqkv | cast w_out | rope table ----
__global__ __launch_bounds__(256) void prep_kernel(const float* __restrict__ w,
                                                   const float* __restrict__ qa,
                                                   const float* __restrict__ qb,
                                                   const float* __restrict__ va,
                                                   const float* __restrict__ vb,
                                                   const float* __restrict__ wout,
                                                   unsigned short* __restrict__ wqkvb,
                                                   unsigned short* __restrict__ woutb,
                                                   float* __restrict__ ropec,
                                                   float* __restrict__ ropes) {
    const int blk = blockIdx.x;
    const int tid = threadIdx.x;
    if (blk < 3 * Dd) {
        const int e = blk;
        const int d0 = tid * 4;
        __shared__ float br[Rr];
        const bool isq = (e < Dd);
        const bool isv = (e >= 2 * Dd);
        const float* bsrc = isq ? (qb + (size_t)e * Rr)
                                : (isv ? (vb + (size_t)(e - 2 * Dd) * Rr) : nullptr);
        const float* asrc = isq ? qa : va;
        if (bsrc && tid < Rr) br[tid] = bsrc[tid];
        __syncthreads();
        float acc[4] = {0.f, 0.f, 0.f, 0.f};
        if (bsrc) {
#pragma unroll 8
            for (int r = 0; r < Rr; ++r) {
                float4 av = *(const float4*)(asrc + (size_t)r * Dd + d0);
                acc[0] += br[r] * av.x; acc[1] += br[r] * av.y;
                acc[2] += br[r] * av.z; acc[3] += br[r] * av.w;
            }
        }
        float4 wv = *(const float4*)(w + (size_t)e * Dd + d0);
        ushort4 o;
        o.x = f2bf(wv.x + LORA_SCALE * acc[0]);
        o.y = f2bf(wv.y + LORA_SCALE * acc[1]);
        o.z = f2bf(wv.z + LORA_SCALE * acc[2]);
        o.w = f2bf(wv.w + LORA_SCALE * acc[3]);
        *(ushort4*)(wqkvb + (size_t)e * Dd + d0) = o;
    } else if (blk < 4 * Dd) {
        int i = ((blk - 3 * Dd) * 256 + tid) * 4;
        float4 v = *(const float4*)(wout + i);
        ushort4 o;
        o.x = f2bf(v.x); o.y = f2bf(v.y); o.z = f2bf(v.z); o.w = f2bf(v.w);
        *(ushort4*)(woutb + i) = o;
    } else {
        int i = (blk - 4 * Dd) * 256 + tid;    // over Ls*32
        int l = i >> 5;
        int f = i & 31;
        float invf = powf(10000.0f, -(float)f * (1.0f / 32.0f));
        float ang = (float)l * invf;
        float s, c;
        sincosf(ang, &s, &c);
        ropec[i] = c;
        ropes[i] = s;
    }
}

// ---------------- 1. LayerNorm(x) -> h (bf16) ----------------
__global__ __launch_bounds__(256) void ln_x_kernel(const float* __restrict__ x,
                                                   const float* __restrict__ w,
                                                   const float* __restrict__ b,
                                                   unsigned short* __restrict__ hb) {
    const int row = blockIdx.x;
    const int tid = threadIdx.x;
    __shared__ float red[4];
    float4 xv = *(const float4*)(x + (size_t)row * Dd + tid * 4);
    float v[4] = {xv.x, xv.y, xv.z, xv.w};
    float s = v[0] + v[1] + v[2] + v[3];
    float mean = block_sum_256(s, red) * (1.0f / Dd);
    float sq = 0.f;
#pragma unroll
    for (int j = 0; j < 4; ++j) {
        v[j] -= mean;
        sq += v[j] * v[j];
    }
    float var = block_sum_256(sq, red) * (1.0f / Dd);
    float rs = rsqrtf(var + LN_EPS);
    ushort4 o;
    unsigned short* op = (unsigned short*)&o;
#pragma unroll
    for (int j = 0; j < 4; ++j) {
        int d = tid * 4 + j;
        op[j] = f2bf(v[j] * rs * w[d] + b[d]);
    }
    *(ushort4*)(hb + (size_t)row * Dd + tid * 4) = o;
}

// ---------------- 2. MFMA GEMM: C[M,N] = A[M,K] * B[N,K]^T ----------------
template <bool OUT_BF16>
__global__ __launch_bounds__(256) void gemm_bt_mfma(const unsigned short* __restrict__ A,
                                                    const unsigned short* __restrict__ B,
                                                    void* __restrict__ Cv,
                                                    int M, int N, int K) {
    __shared__ short As[128 * 64];
    __shared__ short Bs[128 * 64];
    const int tid = threadIdx.x;
    const int w = tid >> 6, lane = tid & 63, quad = lane >> 4, l15 = lane & 15;
    const int m0 = blockIdx.y * 128, n0 = blockIdx.x * 128;
    const int wm = (w & 1) * 64, wn = (w >> 1) * 64;
    f32x4 acc[4][4];
#pragma unroll
    for (int i = 0; i < 4; ++i)
#pragma unroll
        for (int j = 0; j < 4; ++j) acc[i][j] = f32x4{0.f, 0.f, 0.f, 0.f};

    for (int k0 = 0; k0 < K; k0 += 64) {
#pragma unroll
        for (int j = 0; j < 4; ++j) {
            int c = tid + j * 256;
            int row = c >> 3;
            int jg = (c & 7) ^ (row & 7);
            async_copy16(A + (size_t)(m0 + row) * K + k0 + jg * 8, As + c * 8);
        }
#pragma unroll
        for (int j = 0; j < 4; ++j) {
            int c = tid + j * 256;
            int row = c >> 3;
            int jg = (c & 7) ^ (row & 7);
            async_copy16(B + (size_t)(n0 + row) * K + k0 + jg * 8, Bs + c * 8);
        }
        __syncthreads();
#pragma unroll
        for (int ks = 0; ks < 2; ++ks) {
            bf16x8 a[4], b[4];
#pragma unroll
            for (int mi = 0; mi < 4; ++mi) {
                int row = wm + mi * 16 + l15;
                int ch = (ks * 4 + quad) ^ (row & 7);
                a[mi] = *(const bf16x8*)&As[row * 64 + ch * 8];
            }
#pragma unroll
            for (int ni = 0; ni < 4; ++ni) {
                int row = wn + ni * 16 + l15;
                int ch = (ks * 4 + quad) ^ (row & 7);
                b[ni] = *(const bf16x8*)&Bs[row * 64 + ch * 8];
            }
#pragma unroll
            for (int mi = 0; mi < 4; ++mi)
#pragma unroll
                for (int ni = 0; ni < 4; ++ni)
                    acc[mi][ni] = __builtin_amdgcn_mfma_f32_16x16x32_bf16(a[mi], b[ni], acc[mi][ni], 0, 0, 0);
        }
        __syncthreads();
    }
    if (OUT_BF16) {
        unsigned short* C = (unsigned short*)Cv;
#pragma unroll
        for (int mi = 0; mi < 4; ++mi)
#pragma unroll
            for (int ni = 0; ni < 4; ++ni)
#pragma unroll
                for (int r = 0; r < 4; ++r)
                    C[(size_t)(m0 + wm + mi * 16 + quad * 4 + r) * N + n0 + wn + ni * 16 + l15] =
                        f2bf(acc[mi][ni][r]);
    } else {
        float* C = (float*)Cv;
#pragma unroll
        for (int mi = 0; mi < 4; ++mi)
#pragma unroll
            for (int ni = 0; ni < 4; ++ni)
#pragma unroll
                for (int r = 0; r < 4; ++r)
                    C[(size_t)(m0 + wm + mi * 16 + quad * 4 + r) * N + n0 + wn + ni * 16 + l15] =
                        acc[mi][ni][r];
    }
}

// ---------------- 3. Q/K finalize: LN + RoPE -> bf16 [B,H,L,DH] ----------------
__global__ __launch_bounds__(256) void qkv_final_kernel(const unsigned short* __restrict__ qkvb,
                                                        const float* __restrict__ qlnw,
                                                        const float* __restrict__ klnw,
                                                        const float* __restrict__ ropec,
                                                        const float* __restrict__ ropes,
                                                        unsigned short* __restrict__ qt,
                                                        unsigned short* __restrict__ kt) {
    const int row = blockIdx.x;
    const int b = row >> 11;
    const int l = row & (Ls - 1);
    const int tid = threadIdx.x;
    __shared__ float yrow[Dd];
    __shared__ float red[4];

    const int d0 = tid * 4;
    const int hh = d0 >> 6;
    const int dh0 = d0 & 63;
    float cs4[4], sn4[4];
#pragma unroll
    for (int j = 0; j < 4; ++j) {
        int f = (dh0 + j) & 31;
        cs4[j] = ropec[l * 32 + f];
        sn4[j] = ropes[l * 32 + f];
    }
    const size_t dst_off = (((size_t)(b * Hh + hh)) * Ls + l) * DHh + dh0;

    // ---- Q: LN + RoPE + prescale ----
    {
        ushort4 qv = *(const ushort4*)(qkvb + (size_t)row * (3 * Dd) + d0);
        float v[4] = {bf2f(qv.x), bf2f(qv.y), bf2f(qv.z), bf2f(qv.w)};
        float s = v[0] + v[1] + v[2] + v[3];
        float mean = block_sum_256(s, red) * (1.0f / Dd);
        float sq = 0.f;
#pragma unroll
        for (int j = 0; j < 4; ++j) {
            v[j] -= mean;
            sq += v[j] * v[j];
        }
        float var = block_sum_256(sq, red) * (1.0f / Dd);
        float rs = rsqrtf(var + LN_EPS);
#pragma unroll
        for (int j = 0; j < 4; ++j) yrow[d0 + j] = v[j] * rs * qlnw[d0 + j];
        __syncthreads();
        ushort4 pk;
        unsigned short* pp = (unsigned short*)&pk;
#pragma unroll
        for (int j = 0; j < 4; ++j) {
            int d = d0 + j;
            int dh = dh0 + j;
            float rot = (dh < 32) ? -yrow[d + 32] : yrow[d - 32];
            pp[j] = f2bf((yrow[d] * cs4[j] + rot * sn4[j]) * QSCL);
        }
        *(ushort4*)(qt + dst_off) = pk;
    }
    __syncthreads();  // yrow reuse

    // ---- K: LN + RoPE ----
    {
        ushort4 kv = *(const ushort4*)(qkvb + (size_t)row * (3 * Dd) + Dd + d0);
        float v[4] = {bf2f(kv.x), bf2f(kv.y), bf2f(kv.z), bf2f(kv.w)};
        float s = v[0] + v[1] + v[2] + v[3];
        float mean = block_sum_256(s, red) * (1.0f / Dd);
        float sq = 0.f;
#pragma unroll
        for (int j = 0; j < 4; ++j) {
            v[j] -= mean;
            sq += v[j] * v[j];
        }
        float var = block_sum_256(sq, red) * (1.0f / Dd);
        float rs = rsqrtf(var + LN_EPS);
#pragma unroll
        for (int j = 0; j < 4; ++j) yrow[d0 + j] = v[j] * rs * klnw[d0 + j];
        __syncthreads();
        ushort4 pk;
        unsigned short* pp = (unsigned short*)&pk;
#pragma unroll
        for (int j = 0; j < 4; ++j) {
            int d = d0 + j;
            int dh = dh0 + j;
            float rot = (dh < 32) ? -yrow[d + 32] : yrow[d - 32];
            pp[j] = f2bf(yrow[d] * cs4[j] + rot * sn4[j]);
        }
        *(ushort4*)(kt + dst_off) = pk;
    }
}

// ---------------- 4. V transpose: qkv bf16 v-section -> vtt bf16 [B,H,DH,L] ----
__global__ __launch_bounds__(256) void transpose_v_kernel(const unsigned short* __restrict__ qkvb,
                                                          unsigned short* __restrict__ vtt) {
    const int l0 = blockIdx.x * 64;
    const int h = blockIdx.y;
    const int b = blockIdx.z;
    const int tid = threadIdx.x;
    __shared__ short t[64][72];
    const unsigned short* src = qkvb + (size_t)b * Ls * (3 * Dd) + 2 * Dd + h * 64;
#pragma unroll
    for (int j = 0; j < 2; ++j) {
        int g = tid + j * 256;
        int row = g >> 3;
        int c0 = (g & 7) * 8;
        uint4 vv = *(const uint4*)(src + (size_t)(l0 + row) * (3 * Dd) + c0);
        *(uint4*)&t[row][c0] = vv;
    }
    __syncthreads();
    unsigned short* dst = vtt + ((size_t)(b * Hh + h) * DHh) * Ls;
#pragma unroll
    for (int j = 0; j < 2; ++j) {
        int g = tid + j * 256;
        int dh = g >> 3;
        int lc = (g & 7) * 8;
        ushort4 o0, o1;
        unsigned short* p0 = (unsigned short*)&o0;
        unsigned short* p1 = (unsigned short*)&o1;
#pragma unroll
        for (int i = 0; i < 4; ++i) p0[i] = (unsigned short)t[lc + i][dh];
#pragma unroll
        for (int i = 0; i < 4; ++i) p1[i] = (unsigned short)t[lc + 4 + i][dh];
        *(ushort4*)(dst + (size_t)dh * Ls + l0 + lc) = o0;
        *(ushort4*)(dst + (size_t)dh * Ls + l0 + lc + 4) = o1;
    }
}

// ---------------- 5. MFMA flash attention v4 ---------------------------------
// 128 q-rows/block (2 independent 16-row subtiles per wave), 256 thr, grid 512.
// Single-buffer staging; Q frags register-direct; fixed-reference softmax.
constexpr int PSP = 76;  // Ps pitch

__global__ __launch_bounds__(256) void attn_kernel(const unsigned short* __restrict__ qt,
                                                   const unsigned short* __restrict__ kt,
                                                   const unsigned short* __restrict__ vtt,
                                                   const int* __restrict__ seq_id,
                                                   unsigned short* __restrict__ ctxb) {
    // XCD-swizzled decode: all 16 q-blocks of one (b,h) share id%8
    const int id = blockIdx.x;            // 0..511
    const int c8 = id & 7;
    const int x = (id >> 3) & 15;         // q-block within (b,h)
    const int g4 = id >> 7;               // 0..3
    const int v = c8 + 8 * g4;            // h + 16*b
    const int b = v >> 4;
    const int h = v & 15;
    const int q0 = x * 128;

    const size_t base = ((size_t)(b * Hh + h)) * Ls * DHh;
    const size_t base_v = ((size_t)(b * Hh + h)) * DHh * Ls;
    const int* sid = seq_id + (size_t)b * Ls;

    __shared__ short Ks[64 * 64];
    __shared__ short Vs[64 * 64];
    __shared__ short Ps[8][16 * PSP];     // [wave*2+sub]
    __shared__ int sq_s[128];

    const int tid = threadIdx.x;
    const int w = tid >> 6;
    const int lane = tid & 63;
    const int quad = lane >> 4;
    const int l15 = lane & 15;

    if (tid < 128) sq_s[tid] = sid[q0 + tid];
    const int qmin = sid[q0];
    const int qmax = sid[q0 + 127];

    // Q fragments for both subtiles, direct from global
    bf16x8 a0[2], a1[2];
#pragma unroll
    for (int sub = 0; sub < 2; ++sub) {
        int qrow = q0 + sub * 64 + w * 16 + l15;
        a0[sub] = *(const bf16x8*)(qt + base + (size_t)qrow * DHh + quad * 8);
        a1[sub] = *(const bf16x8*)(qt + base + (size_t)qrow * DHh + 32 + quad * 8);
    }

    // contiguous needed-tile range via ballot (tiles 0..31)
    bool need = false;
    if (lane < 32) {
        int kmn = sid[lane * 64];
        int kmx = sid[lane * 64 + 63];
        need = (kmn <= qmax) && (kmx >= qmin);
    }
    unsigned long long bmask = __ballot(need);
    const int t0 = __builtin_ctzll(bmask);
    const int t1 = 64 - __builtin_clzll(bmask);

    float lsum[2][4] = {{0.f, 0.f, 0.f, 0.f}, {0.f, 0.f, 0.f, 0.f}};
    f32x4 O[2][4];
#pragma unroll
    for (int sub = 0; sub < 2; ++sub)
#pragma unroll
        for (int r = 0; r < 4; ++r) O[sub][r] = f32x4{0.f, 0.f, 0.f, 0.f};

    for (int t = t0; t < t1; ++t) {
        const int k0 = t * 64;
        __syncthreads();   // previous tile's readers done (covers sq_s init too)
#pragma unroll
        for (int j = 0; j < 2; ++j) {
            int cc = tid + j * 256;
            int row = cc >> 3;
            int jg = (cc & 7) ^ (row & 7);
            async_copy16(kt + base + (size_t)(k0 + row) * DHh + jg * 8, &Ks[cc * 8]);
            async_copy16(vtt + base_v + (size_t)row * Ls + k0 + jg * 8, &Vs[cc * 8]);
        }
        __syncthreads();   // drain

        // ---- S = Q K^T for both subtiles (independent chains) ----
        f32x4 s[2][4];
#pragma unroll
        for (int kg = 0; kg < 4; ++kg) {
            int krow = kg * 16 + l15;
            bf16x8 b0 = *(const bf16x8*)&Ks[krow * 64 + ((0 + quad) ^ (krow & 7)) * 8];
            bf16x8 b1 = *(const bf16x8*)&Ks[krow * 64 + ((4 + quad) ^ (krow & 7)) * 8];
#pragma unroll
            for (int sub = 0; sub < 2; ++sub) {
                f32x4 acc = {0.f, 0.f, 0.f, 0.f};
                acc = __builtin_amdgcn_mfma_f32_16x16x32_bf16(a0[sub], b0, acc, 0, 0, 0);
                acc = __builtin_amdgcn_mfma_f32_16x16x32_bf16(a1[sub], b1, acc, 0, 0, 0);
                s[sub][kg] = acc;
            }
        }
        // mask only boundary tiles
        const int kmn = sid[k0];
        const int kmx = sid[k0 + 63];
        const bool nomask = (kmn == kmx) && (qmin == qmax) && (kmn == qmin);
        if (!nomask) {
#pragma unroll
            for (int sub = 0; sub < 2; ++sub) {
                int sqv[4];
#pragma unroll
                for (int r = 0; r < 4; ++r) sqv[r] = sq_s[sub * 64 + w * 16 + quad * 4 + r];
#pragma unroll
                for (int kg = 0; kg < 4; ++kg) {
                    int skv = sid[k0 + kg * 16 + l15];
#pragma unroll
                    for (int r = 0; r < 4; ++r)
                        if (sqv[r] != skv) s[sub][kg][r] = -3.0e38f;
                }
            }
        }
        // p = exp2(s); l partials; P -> per-wave/sub LDS
#pragma unroll
        for (int sub = 0; sub < 2; ++sub) {
#pragma unroll
            for (int kg = 0; kg < 4; ++kg)
#pragma unroll
                for (int r = 0; r < 4; ++r)
                    s[sub][kg][r] = __builtin_amdgcn_exp2f(s[sub][kg][r]);
#pragma unroll
            for (int r = 0; r < 4; ++r)
                lsum[sub][r] += s[sub][0][r] + s[sub][1][r] + s[sub][2][r] + s[sub][3][r];
#pragma unroll
            for (int kg = 0; kg < 4; ++kg)
#pragma unroll
                for (int r = 0; r < 4; ++r)
                    Ps[w * 2 + sub][(quad * 4 + r) * PSP + kg * 16 + l15] =
                        (short)f2bf(s[sub][kg][r]);
        }
        // ---- O += P V (both subtiles) ----
        bf16x8 pa0[2], pa1[2];
#pragma unroll
        for (int sub = 0; sub < 2; ++sub) {
            pa0[sub] = *(const bf16x8*)&Ps[w * 2 + sub][l15 * PSP + quad * 8];
            pa1[sub] = *(const bf16x8*)&Ps[w * 2 + sub][l15 * PSP + 32 + quad * 8];
        }
#pragma unroll
        for (int ng = 0; ng < 4; ++ng) {
            int vrow = ng * 16 + l15;   // dh
            bf16x8 vb0 = *(const bf16x8*)&Vs[vrow * 64 + ((0 + quad) ^ (vrow & 7)) * 8];
            bf16x8 vb1 = *(const bf16x8*)&Vs[vrow * 64 + ((4 + quad) ^ (vrow & 7)) * 8];
#pragma unroll
            for (int sub = 0; sub < 2; ++sub) {
                O[sub][ng] = __builtin_amdgcn_mfma_f32_16x16x32_bf16(pa0[sub], vb0, O[sub][ng], 0, 0, 0);
                O[sub][ng] = __builtin_amdgcn_mfma_f32_16x16x32_bf16(pa1[sub], vb1, O[sub][ng], 0, 0, 0);
            }
        }
    }

    // deferred l reduction + epilogue for both subtiles
#pragma unroll
    for (int sub = 0; sub < 2; ++sub) {
#pragma unroll
        for (int off = 1; off < 16; off <<= 1)
#pragma unroll
            for (int r = 0; r < 4; ++r)
                lsum[sub][r] += __shfl_xor(lsum[sub][r], off, 64);
        float inv_l[4];
#pragma unroll
        for (int r = 0; r < 4; ++r) inv_l[r] = 1.0f / lsum[sub][r];
#pragma unroll
        for (int ng = 0; ng < 4; ++ng)
#pragma unroll
            for (int r = 0; r < 4; ++r) {
                int q = q0 + sub * 64 + w * 16 + quad * 4 + r;
                ctxb[((size_t)b * Ls + q) * Dd + h * DHh + ng * 16 + l15] =
                    f2bf(O[sub][ng][r] * inv_l[r]);
            }
    }
}

// ---------------- launcher ----------------
extern "C" void kernel_launch(void* const* d_in, const int* in_sizes, int n_in,
                              void* d_out, int out_size, void* d_ws, size_t ws_size,
                              hipStream_t stream) {
    const float* x = (const float*)d_in[0];
    const int* seq_id = (const int*)d_in[1];
    const float* ln_w = (const float*)d_in[2];
    const float* ln_b = (const float*)d_in[3];
    const float* w_qkv = (const float*)d_in[4];
    const float* q_lora_a = (const float*)d_in[5];
    const float* q_lora_b = (const float*)d_in[6];
    const float* v_lora_a = (const float*)d_in[7];
    const float* v_lora_b = (const float*)d_in[8];
    const float* q_ln_w = (const float*)d_in[9];
    const float* k_ln_w = (const float*)d_in[10];
    const float* w_out = (const float*)d_in[11];
    float* out = (float*)d_out;

    const size_t SZ = (size_t)BL * Dd;        // 4M elements
    float* p = (float*)d_ws;
    float* ropec = p;          p += (size_t)Ls * 32;
    float* ropes = p;          p += (size_t)Ls * 32;
    unsigned short* ub = (unsigned short*)p;
    unsigned short* qkvb = ub; ub += 3 * SZ;  // bf16 [BL, 3D]
    unsigned short* hb = ub;   ub += SZ;      // bf16 [BL, D]
    unsigned short* qt = ub;   ub += SZ;      // bf16 [B,H,L,DH] (prescaled)
    unsigned short* kt = ub;   ub += SZ;
    unsigned short* vtt = ub;  ub += SZ;      // bf16 [B,H,DH,L]
    unsigned short* ctxb = ub; ub += SZ;      // bf16 [BL, D]
    unsigned short* wqkvb = ub; ub += (size_t)3 * Dd * Dd;
    unsigned short* woutb = ub; ub += (size_t)Dd * Dd;

    prep_kernel<<<4 * Dd + 256, 256, 0, stream>>>(w_qkv, q_lora_a, q_lora_b,
                                                  v_lora_a, v_lora_b, w_out,
                                                  wqkvb, woutb, ropec, ropes);
    ln_x_kernel<<<BL, 256, 0, stream>>>(x, ln_w, ln_b, hb);
    {
        dim3 g(3 * Dd / 128, BL / 128);
        gemm_bt_mfma<true><<<g, 256, 0, stream>>>(hb, wqkvb, qkvb, BL, 3 * Dd, Dd);
    }
    qkv_final_kernel<<<BL, 256, 0, stream>>>(qkvb, q_ln_w, k_ln_w,
                                             ropec, ropes, qt, kt);
    {
        dim3 g(Ls / 64, Hh, Bb);
        transpose_v_kernel<<<g, 256, 0, stream>>>(qkvb, vtt);
    }
    attn_kernel<<<512, 256, 0, stream>>>(qt, kt, vtt, seq_id, ctxb);
    {
        dim3 g(Dd / 128, BL / 128);
        gemm_bt_mfma<false><<<g, 256, 0, stream>>>(ctxb, woutb, out, BL, Dd, Dd);
    }
}

// Round 12
// 206.964 us; speedup vs baseline: 1.0824x; 1.0755x over previous
//
#include <hip/hip_runtime.h>
#include <hip/hip_bf16.h>
#include <cmath>

// Problem constants (fixed by reference)
constexpr int Bb = 2;
constexpr int Ls = 2048;
constexpr int Dd = 1024;
constexpr int Hh = 16;
constexpr int DHh = 64;
constexpr int Rr = 32;
constexpr int BL = Bb * Ls;          // 4096
constexpr float LORA_SCALE = 2.0f;   // 64/32
constexpr float LN_EPS = 1e-5f;
constexpr float ATTN_SCALE = 0.125f; // 1/sqrt(64)
constexpr float LOG2E = 1.4426950408889634f;
constexpr float QSCL = ATTN_SCALE * LOG2E;  // folded into qt

typedef __attribute__((ext_vector_type(8))) short bf16x8;
typedef __attribute__((ext_vector_type(4))) float f32x4;

__device__ __forceinline__ unsigned short f2bf(float f) {
    __hip_bfloat16 b = __float2bfloat16(f);
    return *reinterpret_cast<unsigned short*>(&b);
}
__device__ __forceinline__ float bf2f(unsigned short u) {
    unsigned int x = ((unsigned int)u) << 16;
    return __uint_as_float(x);
}
__device__ __forceinline__ void async_copy16(const void* g, void* l) {
    __builtin_amdgcn_global_load_lds(
        (__attribute__((address_space(1))) void*)(void*)(size_t)g,
        (__attribute__((address_space(3))) void*)l, 16, 0, 0);
}

// ---------------- block-wide sum over 256 threads ----------------
__device__ __forceinline__ float block_sum_256(float v, float* red) {
#pragma unroll
    for (int o = 32; o > 0; o >>= 1) v += __shfl_down(v, o, 64);
    const int lane = threadIdx.x & 63;
    const int wid = threadIdx.x >> 6;
    if (lane == 0) red[wid] = v;
    __syncthreads();
    float s = red[0] + red[1] + red[2] + red[3];
    __syncthreads();
    return s;
}

// paired sum: reduces two values with one barrier round
__device__ __forceinline__ float2 block_sum2_256(float a, float b, float* red) {
#pragma unroll
    for (int o = 32; o > 0; o >>= 1) {
        a += __shfl_down(a, o, 64);
        b += __shfl_down(b, o, 64);
    }
    const int lane = threadIdx.x & 63;
    const int wid = threadIdx.x >> 6;
    if (lane == 0) { red[wid] = a; red[4 + wid] = b; }
    __syncthreads();
    float ra = red[0] + red[1] + red[2] + red[3];
    float rb = red[4] + red[5] + red[6] + red[7];
    __syncthreads();
    return make_float2(ra, rb);
}

// ---------------- 0. fused prep: merge-wqkv | cast w_out | rope | ln_x --------
// grid: [0,3K) merge, [3K,4K) cast, [4K,4K+256) rope, [4K+256, +BL) ln_x rows.
__global__ __launch_bounds__(256) void prep_ln_kernel(const float* __restrict__ w,
                                                      const float* __restrict__ qa,
                                                      const float* __restrict__ qb,
                                                      const float* __restrict__ va,
                                                      const float* __restrict__ vb,
                                                      const float* __restrict__ wout,
                                                      const float* __restrict__ x,
                                                      const float* __restrict__ lnw,
                                                      const float* __restrict__ lnb,
                                                      unsigned short* __restrict__ wqkvb,
                                                      unsigned short* __restrict__ woutb,
                                                      float* __restrict__ ropec,
                                                      float* __restrict__ ropes,
                                                      unsigned short* __restrict__ hb) {
    const int blk = blockIdx.x;
    const int tid = threadIdx.x;
    if (blk < 3 * Dd) {
        const int e = blk;
        const int d0 = tid * 4;
        __shared__ float br[Rr];
        const bool isq = (e < Dd);
        const bool isv = (e >= 2 * Dd);
        const float* bsrc = isq ? (qb + (size_t)e * Rr)
                                : (isv ? (vb + (size_t)(e - 2 * Dd) * Rr) : nullptr);
        const float* asrc = isq ? qa : va;
        if (bsrc && tid < Rr) br[tid] = bsrc[tid];
        __syncthreads();
        float acc[4] = {0.f, 0.f, 0.f, 0.f};
        if (bsrc) {
#pragma unroll 8
            for (int r = 0; r < Rr; ++r) {
                float4 av = *(const float4*)(asrc + (size_t)r * Dd + d0);
                acc[0] += br[r] * av.x; acc[1] += br[r] * av.y;
                acc[2] += br[r] * av.z; acc[3] += br[r] * av.w;
            }
        }
        float4 wv = *(const float4*)(w + (size_t)e * Dd + d0);
        ushort4 o;
        o.x = f2bf(wv.x + LORA_SCALE * acc[0]);
        o.y = f2bf(wv.y + LORA_SCALE * acc[1]);
        o.z = f2bf(wv.z + LORA_SCALE * acc[2]);
        o.w = f2bf(wv.w + LORA_SCALE * acc[3]);
        *(ushort4*)(wqkvb + (size_t)e * Dd + d0) = o;
    } else if (blk < 4 * Dd) {
        int i = ((blk - 3 * Dd) * 256 + tid) * 4;
        float4 v = *(const float4*)(wout + i);
        ushort4 o;
        o.x = f2bf(v.x); o.y = f2bf(v.y); o.z = f2bf(v.z); o.w = f2bf(v.w);
        *(ushort4*)(woutb + i) = o;
    } else if (blk < 4 * Dd + 256) {
        int i = (blk - 4 * Dd) * 256 + tid;    // over Ls*32
        int l = i >> 5;
        int f = i & 31;
        float invf = powf(10000.0f, -(float)f * (1.0f / 32.0f));
        float ang = (float)l * invf;
        float s, c;
        sincosf(ang, &s, &c);
        ropec[i] = c;
        ropes[i] = s;
    } else {
        // ---- LayerNorm(x) row ----
        const int row = blk - (4 * Dd + 256);
        __shared__ float red[8];
        float4 xv = *(const float4*)(x + (size_t)row * Dd + tid * 4);
        float v[4] = {xv.x, xv.y, xv.z, xv.w};
        float s = v[0] + v[1] + v[2] + v[3];
        float mean = block_sum_256(s, red) * (1.0f / Dd);
        float sq = 0.f;
#pragma unroll
        for (int j = 0; j < 4; ++j) {
            v[j] -= mean;
            sq += v[j] * v[j];
        }
        float var = block_sum_256(sq, red) * (1.0f / Dd);
        float rs = rsqrtf(var + LN_EPS);
        ushort4 o;
        unsigned short* op = (unsigned short*)&o;
#pragma unroll
        for (int j = 0; j < 4; ++j) {
            int d = tid * 4 + j;
            op[j] = f2bf(v[j] * rs * lnw[d] + lnb[d]);
        }
        *(ushort4*)(hb + (size_t)row * Dd + tid * 4) = o;
    }
}

// ---------------- 2. MFMA GEMM 128x128: C[M,N] = A[M,K] * B[N,K]^T, bf16 out --
__global__ __launch_bounds__(256) void gemm_bt_mfma(const unsigned short* __restrict__ A,
                                                    const unsigned short* __restrict__ B,
                                                    unsigned short* __restrict__ C,
                                                    int M, int N, int K) {
    __shared__ short As[128 * 64];
    __shared__ short Bs[128 * 64];
    const int tid = threadIdx.x;
    const int w = tid >> 6, lane = tid & 63, quad = lane >> 4, l15 = lane & 15;
    const int m0 = blockIdx.y * 128, n0 = blockIdx.x * 128;
    const int wm = (w & 1) * 64, wn = (w >> 1) * 64;
    f32x4 acc[4][4];
#pragma unroll
    for (int i = 0; i < 4; ++i)
#pragma unroll
        for (int j = 0; j < 4; ++j) acc[i][j] = f32x4{0.f, 0.f, 0.f, 0.f};

    for (int k0 = 0; k0 < K; k0 += 64) {
#pragma unroll
        for (int j = 0; j < 4; ++j) {
            int c = tid + j * 256;
            int row = c >> 3;
            int jg = (c & 7) ^ (row & 7);
            async_copy16(A + (size_t)(m0 + row) * K + k0 + jg * 8, As + c * 8);
        }
#pragma unroll
        for (int j = 0; j < 4; ++j) {
            int c = tid + j * 256;
            int row = c >> 3;
            int jg = (c & 7) ^ (row & 7);
            async_copy16(B + (size_t)(n0 + row) * K + k0 + jg * 8, Bs + c * 8);
        }
        __syncthreads();
#pragma unroll
        for (int ks = 0; ks < 2; ++ks) {
            bf16x8 a[4], b[4];
#pragma unroll
            for (int mi = 0; mi < 4; ++mi) {
                int row = wm + mi * 16 + l15;
                int ch = (ks * 4 + quad) ^ (row & 7);
                a[mi] = *(const bf16x8*)&As[row * 64 + ch * 8];
            }
#pragma unroll
            for (int ni = 0; ni < 4; ++ni) {
                int row = wn + ni * 16 + l15;
                int ch = (ks * 4 + quad) ^ (row & 7);
                b[ni] = *(const bf16x8*)&Bs[row * 64 + ch * 8];
            }
#pragma unroll
            for (int mi = 0; mi < 4; ++mi)
#pragma unroll
                for (int ni = 0; ni < 4; ++ni)
                    acc[mi][ni] = __builtin_amdgcn_mfma_f32_16x16x32_bf16(a[mi], b[ni], acc[mi][ni], 0, 0, 0);
        }
        __syncthreads();
    }
#pragma unroll
    for (int mi = 0; mi < 4; ++mi)
#pragma unroll
        for (int ni = 0; ni < 4; ++ni)
#pragma unroll
            for (int r = 0; r < 4; ++r)
                C[(size_t)(m0 + wm + mi * 16 + quad * 4 + r) * N + n0 + wn + ni * 16 + l15] =
                    f2bf(acc[mi][ni][r]);
}

// ---------------- 2b. MFMA GEMM 128x64 tile (fp32 out) — for N=1024 out-proj --
// 512 blocks -> 2 blocks/CU (vs 1 with 128x128).
__global__ __launch_bounds__(256) void gemm_bt_mfma_n64(const unsigned short* __restrict__ A,
                                                        const unsigned short* __restrict__ B,
                                                        float* __restrict__ C,
                                                        int M, int N, int K) {
    __shared__ short As[128 * 64];
    __shared__ short Bs[64 * 64];
    const int tid = threadIdx.x;
    const int w = tid >> 6, lane = tid & 63, quad = lane >> 4, l15 = lane & 15;
    const int m0 = blockIdx.y * 128, n0 = blockIdx.x * 64;
    const int wm = (w & 1) * 64, wn = (w >> 1) * 32;
    f32x4 acc[4][2];
#pragma unroll
    for (int i = 0; i < 4; ++i)
#pragma unroll
        for (int j = 0; j < 2; ++j) acc[i][j] = f32x4{0.f, 0.f, 0.f, 0.f};

    for (int k0 = 0; k0 < K; k0 += 64) {
#pragma unroll
        for (int j = 0; j < 4; ++j) {
            int c = tid + j * 256;
            int row = c >> 3;
            int jg = (c & 7) ^ (row & 7);
            async_copy16(A + (size_t)(m0 + row) * K + k0 + jg * 8, As + c * 8);
        }
#pragma unroll
        for (int j = 0; j < 2; ++j) {
            int c = tid + j * 256;
            int row = c >> 3;
            int jg = (c & 7) ^ (row & 7);
            async_copy16(B + (size_t)(n0 + row) * K + k0 + jg * 8, Bs + c * 8);
        }
        __syncthreads();
#pragma unroll
        for (int ks = 0; ks < 2; ++ks) {
            bf16x8 a[4], b[2];
#pragma unroll
            for (int mi = 0; mi < 4; ++mi) {
                int row = wm + mi * 16 + l15;
                int ch = (ks * 4 + quad) ^ (row & 7);
                a[mi] = *(const bf16x8*)&As[row * 64 + ch * 8];
            }
#pragma unroll
            for (int ni = 0; ni < 2; ++ni) {
                int row = wn + ni * 16 + l15;
                int ch = (ks * 4 + quad) ^ (row & 7);
                b[ni] = *(const bf16x8*)&Bs[row * 64 + ch * 8];
            }
#pragma unroll
            for (int mi = 0; mi < 4; ++mi)
#pragma unroll
                for (int ni = 0; ni < 2; ++ni)
                    acc[mi][ni] = __builtin_amdgcn_mfma_f32_16x16x32_bf16(a[mi], b[ni], acc[mi][ni], 0, 0, 0);
        }
        __syncthreads();
    }
#pragma unroll
    for (int mi = 0; mi < 4; ++mi)
#pragma unroll
        for (int ni = 0; ni < 2; ++ni)
#pragma unroll
            for (int r = 0; r < 4; ++r)
                C[(size_t)(m0 + wm + mi * 16 + quad * 4 + r) * N + n0 + wn + ni * 16 + l15] =
                    acc[mi][ni][r];
}

// ---------------- 3. fused Q/K finalize + V transpose -------------------------
// grid: [0,BL) rows (Q/K LN+RoPE); [BL, BL+1024) V-transpose tiles.
__global__ __launch_bounds__(256) void qkv_final_kernel(const unsigned short* __restrict__ qkvb,
                                                        const float* __restrict__ qlnw,
                                                        const float* __restrict__ klnw,
                                                        const float* __restrict__ ropec,
                                                        const float* __restrict__ ropes,
                                                        unsigned short* __restrict__ qt,
                                                        unsigned short* __restrict__ kt,
                                                        unsigned short* __restrict__ vtt) {
    const int blk = blockIdx.x;
    const int tid = threadIdx.x;
    if (blk < BL) {
        const int row = blk;
        const int b = row >> 11;
        const int l = row & (Ls - 1);
        __shared__ float yrowq[Dd];
        __shared__ float yrowk[Dd];
        __shared__ float red[8];

        const int d0 = tid * 4;
        const int hh = d0 >> 6;
        const int dh0 = d0 & 63;
        float cs4[4], sn4[4];
#pragma unroll
        for (int j = 0; j < 4; ++j) {
            int f = (dh0 + j) & 31;
            cs4[j] = ropec[l * 32 + f];
            sn4[j] = ropes[l * 32 + f];
        }
        const size_t dst_off = (((size_t)(b * Hh + hh)) * Ls + l) * DHh + dh0;

        ushort4 qv = *(const ushort4*)(qkvb + (size_t)row * (3 * Dd) + d0);
        ushort4 kv = *(const ushort4*)(qkvb + (size_t)row * (3 * Dd) + Dd + d0);
        float vq[4] = {bf2f(qv.x), bf2f(qv.y), bf2f(qv.z), bf2f(qv.w)};
        float vk[4] = {bf2f(kv.x), bf2f(kv.y), bf2f(kv.z), bf2f(kv.w)};
        float2 s2 = block_sum2_256(vq[0] + vq[1] + vq[2] + vq[3],
                                   vk[0] + vk[1] + vk[2] + vk[3], red);
        float mq = s2.x * (1.0f / Dd), mk = s2.y * (1.0f / Dd);
        float sqq = 0.f, sqk = 0.f;
#pragma unroll
        for (int j = 0; j < 4; ++j) {
            vq[j] -= mq; sqq += vq[j] * vq[j];
            vk[j] -= mk; sqk += vk[j] * vk[j];
        }
        float2 v2 = block_sum2_256(sqq, sqk, red);
        float rsq = rsqrtf(v2.x * (1.0f / Dd) + LN_EPS);
        float rsk = rsqrtf(v2.y * (1.0f / Dd) + LN_EPS);
#pragma unroll
        for (int j = 0; j < 4; ++j) {
            yrowq[d0 + j] = vq[j] * rsq * qlnw[d0 + j];
            yrowk[d0 + j] = vk[j] * rsk * klnw[d0 + j];
        }
        __syncthreads();
        ushort4 pq, pk;
        unsigned short* ppq = (unsigned short*)&pq;
        unsigned short* ppk = (unsigned short*)&pk;
#pragma unroll
        for (int j = 0; j < 4; ++j) {
            int d = d0 + j;
            int dh = dh0 + j;
            float rotq = (dh < 32) ? -yrowq[d + 32] : yrowq[d - 32];
            float rotk = (dh < 32) ? -yrowk[d + 32] : yrowk[d - 32];
            ppq[j] = f2bf((yrowq[d] * cs4[j] + rotq * sn4[j]) * QSCL);
            ppk[j] = f2bf(yrowk[d] * cs4[j] + rotk * sn4[j]);
        }
        *(ushort4*)(qt + dst_off) = pq;
        *(ushort4*)(kt + dst_off) = pk;
    } else {
        // ---- V transpose tile ----
        const int t2 = blk - BL;               // 0..1023
        const int l0 = (t2 & 31) * 64;
        const int h = (t2 >> 5) & 15;
        const int b = t2 >> 9;
        __shared__ short t[64][72];
        const unsigned short* src = qkvb + (size_t)b * Ls * (3 * Dd) + 2 * Dd + h * 64;
#pragma unroll
        for (int j = 0; j < 2; ++j) {
            int g = tid + j * 256;
            int row = g >> 3;
            int c0 = (g & 7) * 8;
            uint4 vv = *(const uint4*)(src + (size_t)(l0 + row) * (3 * Dd) + c0);
            *(uint4*)&t[row][c0] = vv;
        }
        __syncthreads();
        unsigned short* dst = vtt + ((size_t)(b * Hh + h) * DHh) * Ls;
#pragma unroll
        for (int j = 0; j < 2; ++j) {
            int g = tid + j * 256;
            int dh = g >> 3;
            int lc = (g & 7) * 8;
            ushort4 o0, o1;
            unsigned short* p0 = (unsigned short*)&o0;
            unsigned short* p1 = (unsigned short*)&o1;
#pragma unroll
            for (int i = 0; i < 4; ++i) p0[i] = (unsigned short)t[lc + i][dh];
#pragma unroll
            for (int i = 0; i < 4; ++i) p1[i] = (unsigned short)t[lc + 4 + i][dh];
            *(ushort4*)(dst + (size_t)dh * Ls + l0 + lc) = o0;
            *(ushort4*)(dst + (size_t)dh * Ls + l0 + lc + 4) = o1;
        }
    }
}

// ---------------- 5. MFMA flash attention (R11-proven) ------------------------
constexpr int PSP = 76;  // Ps pitch

__global__ __launch_bounds__(256) void attn_kernel(const unsigned short* __restrict__ qt,
                                                   const unsigned short* __restrict__ kt,
                                                   const unsigned short* __restrict__ vtt,
                                                   const int* __restrict__ seq_id,
                                                   unsigned short* __restrict__ ctxb) {
    const int id = blockIdx.x;            // 0..511
    const int c8 = id & 7;
    const int x = (id >> 3) & 15;
    const int g4 = id >> 7;
    const int v = c8 + 8 * g4;            // h + 16*b
    const int b = v >> 4;
    const int h = v & 15;
    const int q0 = x * 128;

    const size_t base = ((size_t)(b * Hh + h)) * Ls * DHh;
    const size_t base_v = ((size_t)(b * Hh + h)) * DHh * Ls;
    const int* sid = seq_id + (size_t)b * Ls;

    __shared__ short Ks[64 * 64];
    __shared__ short Vs[64 * 64];
    __shared__ short Ps[8][16 * PSP];
    __shared__ int sq_s[128];

    const int tid = threadIdx.x;
    const int w = tid >> 6;
    const int lane = tid & 63;
    const int quad = lane >> 4;
    const int l15 = lane & 15;

    if (tid < 128) sq_s[tid] = sid[q0 + tid];
    const int qmin = sid[q0];
    const int qmax = sid[q0 + 127];

    bf16x8 a0[2], a1[2];
#pragma unroll
    for (int sub = 0; sub < 2; ++sub) {
        int qrow = q0 + sub * 64 + w * 16 + l15;
        a0[sub] = *(const bf16x8*)(qt + base + (size_t)qrow * DHh + quad * 8);
        a1[sub] = *(const bf16x8*)(qt + base + (size_t)qrow * DHh + 32 + quad * 8);
    }

    bool need = false;
    if (lane < 32) {
        int kmn = sid[lane * 64];
        int kmx = sid[lane * 64 + 63];
        need = (kmn <= qmax) && (kmx >= qmin);
    }
    unsigned long long bmask = __ballot(need);
    const int t0 = __builtin_ctzll(bmask);
    const int t1 = 64 - __builtin_clzll(bmask);

    float lsum[2][4] = {{0.f, 0.f, 0.f, 0.f}, {0.f, 0.f, 0.f, 0.f}};
    f32x4 O[2][4];
#pragma unroll
    for (int sub = 0; sub < 2; ++sub)
#pragma unroll
        for (int r = 0; r < 4; ++r) O[sub][r] = f32x4{0.f, 0.f, 0.f, 0.f};

    for (int t = t0; t < t1; ++t) {
        const int k0 = t * 64;
        __syncthreads();
#pragma unroll
        for (int j = 0; j < 2; ++j) {
            int cc = tid + j * 256;
            int row = cc >> 3;
            int jg = (cc & 7) ^ (row & 7);
            async_copy16(kt + base + (size_t)(k0 + row) * DHh + jg * 8, &Ks[cc * 8]);
            async_copy16(vtt + base_v + (size_t)row * Ls + k0 + jg * 8, &Vs[cc * 8]);
        }
        __syncthreads();

        f32x4 s[2][4];
#pragma unroll
        for (int kg = 0; kg < 4; ++kg) {
            int krow = kg * 16 + l15;
            bf16x8 b0 = *(const bf16x8*)&Ks[krow * 64 + ((0 + quad) ^ (krow & 7)) * 8];
            bf16x8 b1 = *(const bf16x8*)&Ks[krow * 64 + ((4 + quad) ^ (krow & 7)) * 8];
#pragma unroll
            for (int sub = 0; sub < 2; ++sub) {
                f32x4 acc = {0.f, 0.f, 0.f, 0.f};
                acc = __builtin_amdgcn_mfma_f32_16x16x32_bf16(a0[sub], b0, acc, 0, 0, 0);
                acc = __builtin_amdgcn_mfma_f32_16x16x32_bf16(a1[sub], b1, acc, 0, 0, 0);
                s[sub][kg] = acc;
            }
        }
        const int kmn = sid[k0];
        const int kmx = sid[k0 + 63];
        const bool nomask = (kmn == kmx) && (qmin == qmax) && (kmn == qmin);
        if (!nomask) {
#pragma unroll
            for (int sub = 0; sub < 2; ++sub) {
                int sqv[4];
#pragma unroll
                for (int r = 0; r < 4; ++r) sqv[r] = sq_s[sub * 64 + w * 16 + quad * 4 + r];
#pragma unroll
                for (int kg = 0; kg < 4; ++kg) {
                    int skv = sid[k0 + kg * 16 + l15];
#pragma unroll
                    for (int r = 0; r < 4; ++r)
                        if (sqv[r] != skv) s[sub][kg][r] = -3.0e38f;
                }
            }
        }
#pragma unroll
        for (int sub = 0; sub < 2; ++sub) {
#pragma unroll
            for (int kg = 0; kg < 4; ++kg)
#pragma unroll
                for (int r = 0; r < 4; ++r)
                    s[sub][kg][r] = __builtin_amdgcn_exp2f(s[sub][kg][r]);
#pragma unroll
            for (int r = 0; r < 4; ++r)
                lsum[sub][r] += s[sub][0][r] + s[sub][1][r] + s[sub][2][r] + s[sub][3][r];
#pragma unroll
            for (int kg = 0; kg < 4; ++kg)
#pragma unroll
                for (int r = 0; r < 4; ++r)
                    Ps[w * 2 + sub][(quad * 4 + r) * PSP + kg * 16 + l15] =
                        (short)f2bf(s[sub][kg][r]);
        }
        bf16x8 pa0[2], pa1[2];
#pragma unroll
        for (int sub = 0; sub < 2; ++sub) {
            pa0[sub] = *(const bf16x8*)&Ps[w * 2 + sub][l15 * PSP + quad * 8];
            pa1[sub] = *(const bf16x8*)&Ps[w * 2 + sub][l15 * PSP + 32 + quad * 8];
        }
#pragma unroll
        for (int ng = 0; ng < 4; ++ng) {
            int vrow = ng * 16 + l15;
            bf16x8 vb0 = *(const bf16x8*)&Vs[vrow * 64 + ((0 + quad) ^ (vrow & 7)) * 8];
            bf16x8 vb1 = *(const bf16x8*)&Vs[vrow * 64 + ((4 + quad) ^ (vrow & 7)) * 8];
#pragma unroll
            for (int sub = 0; sub < 2; ++sub) {
                O[sub][ng] = __builtin_amdgcn_mfma_f32_16x16x32_bf16(pa0[sub], vb0, O[sub][ng], 0, 0, 0);
                O[sub][ng] = __builtin_amdgcn_mfma_f32_16x16x32_bf16(pa1[sub], vb1, O[sub][ng], 0, 0, 0);
            }
        }
    }

#pragma unroll
    for (int sub = 0; sub < 2; ++sub) {
#pragma unroll
        for (int off = 1; off < 16; off <<= 1)
#pragma unroll
            for (int r = 0; r < 4; ++r)
                lsum[sub][r] += __shfl_xor(lsum[sub][r], off, 64);
        float inv_l[4];
#pragma unroll
        for (int r = 0; r < 4; ++r) inv_l[r] = 1.0f / lsum[sub][r];
#pragma unroll
        for (int ng = 0; ng < 4; ++ng)
#pragma unroll
            for (int r = 0; r < 4; ++r) {
                int q = q0 + sub * 64 + w * 16 + quad * 4 + r;
                ctxb[((size_t)b * Ls + q) * Dd + h * DHh + ng * 16 + l15] =
                    f2bf(O[sub][ng][r] * inv_l[r]);
            }
    }
}

// ---------------- launcher ----------------
extern "C" void kernel_launch(void* const* d_in, const int* in_sizes, int n_in,
                              void* d_out, int out_size, void* d_ws, size_t ws_size,
                              hipStream_t stream) {
    const float* x = (const float*)d_in[0];
    const int* seq_id = (const int*)d_in[1];
    const float* ln_w = (const float*)d_in[2];
    const float* ln_b = (const float*)d_in[3];
    const float* w_qkv = (const float*)d_in[4];
    const float* q_lora_a = (const float*)d_in[5];
    const float* q_lora_b = (const float*)d_in[6];
    const float* v_lora_a = (const float*)d_in[7];
    const float* v_lora_b = (const float*)d_in[8];
    const float* q_ln_w = (const float*)d_in[9];
    const float* k_ln_w = (const float*)d_in[10];
    const float* w_out = (const float*)d_in[11];
    float* out = (float*)d_out;

    const size_t SZ = (size_t)BL * Dd;        // 4M elements
    float* p = (float*)d_ws;
    float* ropec = p;          p += (size_t)Ls * 32;
    float* ropes = p;          p += (size_t)Ls * 32;
    unsigned short* ub = (unsigned short*)p;
    unsigned short* qkvb = ub; ub += 3 * SZ;  // bf16 [BL, 3D]
    unsigned short* hb = ub;   ub += SZ;      // bf16 [BL, D]
    unsigned short* qt = ub;   ub += SZ;      // bf16 [B,H,L,DH] (prescaled)
    unsigned short* kt = ub;   ub += SZ;
    unsigned short* vtt = ub;  ub += SZ;      // bf16 [B,H,DH,L]
    unsigned short* ctxb = ub; ub += SZ;      // bf16 [BL, D]
    unsigned short* wqkvb = ub; ub += (size_t)3 * Dd * Dd;
    unsigned short* woutb = ub; ub += (size_t)Dd * Dd;

    prep_ln_kernel<<<4 * Dd + 256 + BL, 256, 0, stream>>>(
        w_qkv, q_lora_a, q_lora_b, v_lora_a, v_lora_b, w_out,
        x, ln_w, ln_b, wqkvb, woutb, ropec, ropes, hb);
    {
        dim3 g(3 * Dd / 128, BL / 128);
        gemm_bt_mfma<<<g, 256, 0, stream>>>(hb, wqkvb, qkvb, BL, 3 * Dd, Dd);
    }
    qkv_final_kernel<<<BL + 1024, 256, 0, stream>>>(qkvb, q_ln_w, k_ln_w,
                                                    ropec, ropes, qt, kt, vtt);
    attn_kernel<<<512, 256, 0, stream>>>(qt, kt, vtt, seq_id, ctxb);
    {
        dim3 g(Dd / 64, BL / 128);
        gemm_bt_mfma_n64<<<g, 256, 0, stream>>>(ctxb, woutb, out, BL, Dd, Dd);
    }
}

// Round 13
// 203.782 us; speedup vs baseline: 1.0993x; 1.0156x over previous
//
#include <hip/hip_runtime.h>
#include <hip/hip_bf16.h>
#include <cmath>

// Problem constants (fixed by reference)
constexpr int Bb = 2;
constexpr int Ls = 2048;
constexpr int Dd = 1024;
constexpr int Hh = 16;
constexpr int DHh = 64;
constexpr int Rr = 32;
constexpr int BL = Bb * Ls;          // 4096
constexpr float LORA_SCALE = 2.0f;   // 64/32
constexpr float LN_EPS = 1e-5f;
constexpr float ATTN_SCALE = 0.125f; // 1/sqrt(64)
constexpr float LOG2E = 1.4426950408889634f;
constexpr float QSCL = ATTN_SCALE * LOG2E;  // folded into qt

typedef __attribute__((ext_vector_type(8))) short bf16x8;
typedef __attribute__((ext_vector_type(4))) float f32x4;

__device__ __forceinline__ unsigned short f2bf(float f) {
    __hip_bfloat16 b = __float2bfloat16(f);
    return *reinterpret_cast<unsigned short*>(&b);
}
__device__ __forceinline__ float bf2f(unsigned short u) {
    unsigned int x = ((unsigned int)u) << 16;
    return __uint_as_float(x);
}
__device__ __forceinline__ void async_copy16(const void* g, void* l) {
    __builtin_amdgcn_global_load_lds(
        (__attribute__((address_space(1))) void*)(void*)(size_t)g,
        (__attribute__((address_space(3))) void*)l, 16, 0, 0);
}

// ---------------- block-wide sum over 256 threads (merge branch only) --------
__device__ __forceinline__ float block_sum_256(float v, float* red) {
#pragma unroll
    for (int o = 32; o > 0; o >>= 1) v += __shfl_down(v, o, 64);
    const int lane = threadIdx.x & 63;
    const int wid = threadIdx.x >> 6;
    if (lane == 0) red[wid] = v;
    __syncthreads();
    float s = red[0] + red[1] + red[2] + red[3];
    __syncthreads();
    return s;
}

// ---------------- 0. fused prep: merge-wqkv | cast w_out | rope | ln_x --------
// grid: [0,3K) merge, [3K,4K) cast, [4K,4K+256) rope, [4K+256, +1024) ln_x
// (wave-per-row: 4 rows/block, no barriers).
__global__ __launch_bounds__(256) void prep_ln_kernel(const float* __restrict__ w,
                                                      const float* __restrict__ qa,
                                                      const float* __restrict__ qb,
                                                      const float* __restrict__ va,
                                                      const float* __restrict__ vb,
                                                      const float* __restrict__ wout,
                                                      const float* __restrict__ x,
                                                      const float* __restrict__ lnw,
                                                      const float* __restrict__ lnb,
                                                      unsigned short* __restrict__ wqkvb,
                                                      unsigned short* __restrict__ woutb,
                                                      float* __restrict__ ropec,
                                                      float* __restrict__ ropes,
                                                      unsigned short* __restrict__ hb) {
    const int blk = blockIdx.x;
    const int tid = threadIdx.x;
    if (blk < 3 * Dd) {
        const int e = blk;
        const int d0 = tid * 4;
        __shared__ float br[Rr];
        const bool isq = (e < Dd);
        const bool isv = (e >= 2 * Dd);
        const float* bsrc = isq ? (qb + (size_t)e * Rr)
                                : (isv ? (vb + (size_t)(e - 2 * Dd) * Rr) : nullptr);
        const float* asrc = isq ? qa : va;
        if (bsrc && tid < Rr) br[tid] = bsrc[tid];
        __syncthreads();
        float acc[4] = {0.f, 0.f, 0.f, 0.f};
        if (bsrc) {
#pragma unroll 8
            for (int r = 0; r < Rr; ++r) {
                float4 av = *(const float4*)(asrc + (size_t)r * Dd + d0);
                acc[0] += br[r] * av.x; acc[1] += br[r] * av.y;
                acc[2] += br[r] * av.z; acc[3] += br[r] * av.w;
            }
        }
        float4 wv = *(const float4*)(w + (size_t)e * Dd + d0);
        ushort4 o;
        o.x = f2bf(wv.x + LORA_SCALE * acc[0]);
        o.y = f2bf(wv.y + LORA_SCALE * acc[1]);
        o.z = f2bf(wv.z + LORA_SCALE * acc[2]);
        o.w = f2bf(wv.w + LORA_SCALE * acc[3]);
        *(ushort4*)(wqkvb + (size_t)e * Dd + d0) = o;
    } else if (blk < 4 * Dd) {
        int i = ((blk - 3 * Dd) * 256 + tid) * 4;
        float4 v = *(const float4*)(wout + i);
        ushort4 o;
        o.x = f2bf(v.x); o.y = f2bf(v.y); o.z = f2bf(v.z); o.w = f2bf(v.w);
        *(ushort4*)(woutb + i) = o;
    } else if (blk < 4 * Dd + 256) {
        int i = (blk - 4 * Dd) * 256 + tid;    // over Ls*32
        int l = i >> 5;
        int f = i & 31;
        float invf = powf(10000.0f, -(float)f * (1.0f / 32.0f));
        float ang = (float)l * invf;
        float s, c;
        sincosf(ang, &s, &c);
        ropec[i] = c;
        ropes[i] = s;
    } else {
        // ---- LayerNorm(x): wave-per-row, no barriers ----
        const int w64 = tid >> 6;
        const int L = tid & 63;
        const int row = (blk - (4 * Dd + 256)) * 4 + w64;
        const float* xr = x + (size_t)row * Dd;
        float4 v4[4];
        float v[16];
#pragma unroll
        for (int c = 0; c < 4; ++c) {
            v4[c] = *(const float4*)(xr + c * 256 + L * 4);
            v[c * 4 + 0] = v4[c].x; v[c * 4 + 1] = v4[c].y;
            v[c * 4 + 2] = v4[c].z; v[c * 4 + 3] = v4[c].w;
        }
        float s = 0.f;
#pragma unroll
        for (int j = 0; j < 16; ++j) s += v[j];
#pragma unroll
        for (int off = 1; off < 64; off <<= 1) s += __shfl_xor(s, off, 64);
        float mean = s * (1.0f / Dd);
        float sq = 0.f;
#pragma unroll
        for (int j = 0; j < 16; ++j) {
            v[j] -= mean;
            sq += v[j] * v[j];
        }
#pragma unroll
        for (int off = 1; off < 64; off <<= 1) sq += __shfl_xor(sq, off, 64);
        float rs = rsqrtf(sq * (1.0f / Dd) + LN_EPS);
        unsigned short* hr = hb + (size_t)row * Dd;
#pragma unroll
        for (int c = 0; c < 4; ++c) {
            int d = c * 256 + L * 4;
            float4 wv = *(const float4*)(lnw + d);
            float4 bv = *(const float4*)(lnb + d);
            ushort4 o;
            o.x = f2bf(v[c * 4 + 0] * rs * wv.x + bv.x);
            o.y = f2bf(v[c * 4 + 1] * rs * wv.y + bv.y);
            o.z = f2bf(v[c * 4 + 2] * rs * wv.z + bv.z);
            o.w = f2bf(v[c * 4 + 3] * rs * wv.w + bv.w);
            *(ushort4*)(hr + d) = o;
        }
    }
}

// ---------------- 2. MFMA GEMM 128x128: C[M,N] = A[M,K] * B[N,K]^T, bf16 out --
__global__ __launch_bounds__(256) void gemm_bt_mfma(const unsigned short* __restrict__ A,
                                                    const unsigned short* __restrict__ B,
                                                    unsigned short* __restrict__ C,
                                                    int M, int N, int K) {
    __shared__ short As[128 * 64];
    __shared__ short Bs[128 * 64];
    const int tid = threadIdx.x;
    const int w = tid >> 6, lane = tid & 63, quad = lane >> 4, l15 = lane & 15;
    const int m0 = blockIdx.y * 128, n0 = blockIdx.x * 128;
    const int wm = (w & 1) * 64, wn = (w >> 1) * 64;
    f32x4 acc[4][4];
#pragma unroll
    for (int i = 0; i < 4; ++i)
#pragma unroll
        for (int j = 0; j < 4; ++j) acc[i][j] = f32x4{0.f, 0.f, 0.f, 0.f};

    for (int k0 = 0; k0 < K; k0 += 64) {
#pragma unroll
        for (int j = 0; j < 4; ++j) {
            int c = tid + j * 256;
            int row = c >> 3;
            int jg = (c & 7) ^ (row & 7);
            async_copy16(A + (size_t)(m0 + row) * K + k0 + jg * 8, As + c * 8);
        }
#pragma unroll
        for (int j = 0; j < 4; ++j) {
            int c = tid + j * 256;
            int row = c >> 3;
            int jg = (c & 7) ^ (row & 7);
            async_copy16(B + (size_t)(n0 + row) * K + k0 + jg * 8, Bs + c * 8);
        }
        __syncthreads();
#pragma unroll
        for (int ks = 0; ks < 2; ++ks) {
            bf16x8 a[4], b[4];
#pragma unroll
            for (int mi = 0; mi < 4; ++mi) {
                int row = wm + mi * 16 + l15;
                int ch = (ks * 4 + quad) ^ (row & 7);
                a[mi] = *(const bf16x8*)&As[row * 64 + ch * 8];
            }
#pragma unroll
            for (int ni = 0; ni < 4; ++ni) {
                int row = wn + ni * 16 + l15;
                int ch = (ks * 4 + quad) ^ (row & 7);
                b[ni] = *(const bf16x8*)&Bs[row * 64 + ch * 8];
            }
#pragma unroll
            for (int mi = 0; mi < 4; ++mi)
#pragma unroll
                for (int ni = 0; ni < 4; ++ni)
                    acc[mi][ni] = __builtin_amdgcn_mfma_f32_16x16x32_bf16(a[mi], b[ni], acc[mi][ni], 0, 0, 0);
        }
        __syncthreads();
    }
#pragma unroll
    for (int mi = 0; mi < 4; ++mi)
#pragma unroll
        for (int ni = 0; ni < 4; ++ni)
#pragma unroll
            for (int r = 0; r < 4; ++r)
                C[(size_t)(m0 + wm + mi * 16 + quad * 4 + r) * N + n0 + wn + ni * 16 + l15] =
                    f2bf(acc[mi][ni][r]);
}

// ---------------- 2b. MFMA GEMM 128x64 tile (fp32 out) — out-projection -------
__global__ __launch_bounds__(256) void gemm_bt_mfma_n64(const unsigned short* __restrict__ A,
                                                        const unsigned short* __restrict__ B,
                                                        float* __restrict__ C,
                                                        int M, int N, int K) {
    __shared__ short As[128 * 64];
    __shared__ short Bs[64 * 64];
    const int tid = threadIdx.x;
    const int w = tid >> 6, lane = tid & 63, quad = lane >> 4, l15 = lane & 15;
    const int m0 = blockIdx.y * 128, n0 = blockIdx.x * 64;
    const int wm = (w & 1) * 64, wn = (w >> 1) * 32;
    f32x4 acc[4][2];
#pragma unroll
    for (int i = 0; i < 4; ++i)
#pragma unroll
        for (int j = 0; j < 2; ++j) acc[i][j] = f32x4{0.f, 0.f, 0.f, 0.f};

    for (int k0 = 0; k0 < K; k0 += 64) {
#pragma unroll
        for (int j = 0; j < 4; ++j) {
            int c = tid + j * 256;
            int row = c >> 3;
            int jg = (c & 7) ^ (row & 7);
            async_copy16(A + (size_t)(m0 + row) * K + k0 + jg * 8, As + c * 8);
        }
#pragma unroll
        for (int j = 0; j < 2; ++j) {
            int c = tid + j * 256;
            int row = c >> 3;
            int jg = (c & 7) ^ (row & 7);
            async_copy16(B + (size_t)(n0 + row) * K + k0 + jg * 8, Bs + c * 8);
        }
        __syncthreads();
#pragma unroll
        for (int ks = 0; ks < 2; ++ks) {
            bf16x8 a[4], b[2];
#pragma unroll
            for (int mi = 0; mi < 4; ++mi) {
                int row = wm + mi * 16 + l15;
                int ch = (ks * 4 + quad) ^ (row & 7);
                a[mi] = *(const bf16x8*)&As[row * 64 + ch * 8];
            }
#pragma unroll
            for (int ni = 0; ni < 2; ++ni) {
                int row = wn + ni * 16 + l15;
                int ch = (ks * 4 + quad) ^ (row & 7);
                b[ni] = *(const bf16x8*)&Bs[row * 64 + ch * 8];
            }
#pragma unroll
            for (int mi = 0; mi < 4; ++mi)
#pragma unroll
                for (int ni = 0; ni < 2; ++ni)
                    acc[mi][ni] = __builtin_amdgcn_mfma_f32_16x16x32_bf16(a[mi], b[ni], acc[mi][ni], 0, 0, 0);
        }
        __syncthreads();
    }
#pragma unroll
    for (int mi = 0; mi < 4; ++mi)
#pragma unroll
        for (int ni = 0; ni < 2; ++ni)
#pragma unroll
            for (int r = 0; r < 4; ++r)
                C[(size_t)(m0 + wm + mi * 16 + quad * 4 + r) * N + n0 + wn + ni * 16 + l15] =
                    acc[mi][ni][r];
}

// ---------------- 3. fused Q/K finalize (wave-per-row) + V transpose ----------
// grid: [0,1024) -> 4 rows/block Q/K LN+RoPE (no barriers); [1024,2048) V-tiles.
__global__ __launch_bounds__(256) void qkv_final_kernel(const unsigned short* __restrict__ qkvb,
                                                        const float* __restrict__ qlnw,
                                                        const float* __restrict__ klnw,
                                                        const float* __restrict__ ropec,
                                                        const float* __restrict__ ropes,
                                                        unsigned short* __restrict__ qt,
                                                        unsigned short* __restrict__ kt,
                                                        unsigned short* __restrict__ vtt) {
    const int blk = blockIdx.x;
    const int tid = threadIdx.x;
    if (blk < BL / 4) {
        const int w64 = tid >> 6;
        const int L = tid & 63;
        const int row = blk * 4 + w64;
        const int b = row >> 11;
        const int l = row & (Ls - 1);
        const unsigned short* qp = qkvb + (size_t)row * (3 * Dd);
        const unsigned short* kp = qp + Dd;

        // lane holds chunks A: d=L*8..+7 and B: d=512+L*8..+7 (for q and k)
        bf16x8 qA = *(const bf16x8*)(qp + L * 8);
        bf16x8 qB = *(const bf16x8*)(qp + 512 + L * 8);
        bf16x8 kA = *(const bf16x8*)(kp + L * 8);
        bf16x8 kB = *(const bf16x8*)(kp + 512 + L * 8);
        float vq[16], vk[16];
#pragma unroll
        for (int j = 0; j < 8; ++j) {
            vq[j] = bf2f((unsigned short)qA[j]);
            vq[8 + j] = bf2f((unsigned short)qB[j]);
            vk[j] = bf2f((unsigned short)kA[j]);
            vk[8 + j] = bf2f((unsigned short)kB[j]);
        }
        float sq = 0.f, sk = 0.f;
#pragma unroll
        for (int j = 0; j < 16; ++j) { sq += vq[j]; sk += vk[j]; }
#pragma unroll
        for (int off = 1; off < 64; off <<= 1) {
            sq += __shfl_xor(sq, off, 64);
            sk += __shfl_xor(sk, off, 64);
        }
        float mq = sq * (1.0f / Dd), mk = sk * (1.0f / Dd);
        float vvq = 0.f, vvk = 0.f;
#pragma unroll
        for (int j = 0; j < 16; ++j) {
            vq[j] -= mq; vvq += vq[j] * vq[j];
            vk[j] -= mk; vvk += vk[j] * vk[j];
        }
#pragma unroll
        for (int off = 1; off < 64; off <<= 1) {
            vvq += __shfl_xor(vvq, off, 64);
            vvk += __shfl_xor(vvk, off, 64);
        }
        float rsq = rsqrtf(vvq * (1.0f / Dd) + LN_EPS);
        float rsk = rsqrtf(vvk * (1.0f / Dd) + LN_EPS);

        // y = (v - m) * rs * lnw
        float yq[16], yk[16];
        {
            float4 w0 = *(const float4*)(qlnw + L * 8);
            float4 w1 = *(const float4*)(qlnw + L * 8 + 4);
            float4 w2 = *(const float4*)(qlnw + 512 + L * 8);
            float4 w3 = *(const float4*)(qlnw + 512 + L * 8 + 4);
            const float* wp = (const float*)&w0;  // w0,w1 contiguous? no — handle per-vec
            yq[0] = vq[0] * rsq * w0.x; yq[1] = vq[1] * rsq * w0.y;
            yq[2] = vq[2] * rsq * w0.z; yq[3] = vq[3] * rsq * w0.w;
            yq[4] = vq[4] * rsq * w1.x; yq[5] = vq[5] * rsq * w1.y;
            yq[6] = vq[6] * rsq * w1.z; yq[7] = vq[7] * rsq * w1.w;
            yq[8] = vq[8] * rsq * w2.x; yq[9] = vq[9] * rsq * w2.y;
            yq[10] = vq[10] * rsq * w2.z; yq[11] = vq[11] * rsq * w2.w;
            yq[12] = vq[12] * rsq * w3.x; yq[13] = vq[13] * rsq * w3.y;
            yq[14] = vq[14] * rsq * w3.z; yq[15] = vq[15] * rsq * w3.w;
            (void)wp;
        }
        {
            float4 w0 = *(const float4*)(klnw + L * 8);
            float4 w1 = *(const float4*)(klnw + L * 8 + 4);
            float4 w2 = *(const float4*)(klnw + 512 + L * 8);
            float4 w3 = *(const float4*)(klnw + 512 + L * 8 + 4);
            yk[0] = vk[0] * rsk * w0.x; yk[1] = vk[1] * rsk * w0.y;
            yk[2] = vk[2] * rsk * w0.z; yk[3] = vk[3] * rsk * w0.w;
            yk[4] = vk[4] * rsk * w1.x; yk[5] = vk[5] * rsk * w1.y;
            yk[6] = vk[6] * rsk * w1.z; yk[7] = vk[7] * rsk * w1.w;
            yk[8] = vk[8] * rsk * w2.x; yk[9] = vk[9] * rsk * w2.y;
            yk[10] = vk[10] * rsk * w2.z; yk[11] = vk[11] * rsk * w2.w;
            yk[12] = vk[12] * rsk * w3.x; yk[13] = vk[13] * rsk * w3.y;
            yk[14] = vk[14] * rsk * w3.z; yk[15] = vk[15] * rsk * w3.w;
        }

        // rope: f = (d&31) = (L&3)*8 + j, same for both halves.
        float cs[8], sn[8];
        {
            int fbase = l * 32 + (L & 3) * 8;
            float4 c0 = *(const float4*)(ropec + fbase);
            float4 c1 = *(const float4*)(ropec + fbase + 4);
            float4 s0 = *(const float4*)(ropes + fbase);
            float4 s1 = *(const float4*)(ropes + fbase + 4);
            cs[0] = c0.x; cs[1] = c0.y; cs[2] = c0.z; cs[3] = c0.w;
            cs[4] = c1.x; cs[5] = c1.y; cs[6] = c1.z; cs[7] = c1.w;
            sn[0] = s0.x; sn[1] = s0.y; sn[2] = s0.z; sn[3] = s0.w;
            sn[4] = s1.x; sn[5] = s1.y; sn[6] = s1.z; sn[7] = s1.w;
        }
        const float sgn = (L & 4) ? 1.0f : -1.0f;  // dh>=32 ? + : -
        ushort4 oqA0, oqA1, oqB0, oqB1, okA0, okA1, okB0, okB1;
        unsigned short* pqA = (unsigned short*)&oqA0;  // treat pairs below
        // pack helper arrays
        unsigned short outqA[8], outqB[8], outkA[8], outkB[8];
#pragma unroll
        for (int j = 0; j < 8; ++j) {
            float pA = __shfl_xor(yq[j], 4, 64);
            float pB = __shfl_xor(yq[8 + j], 4, 64);
            outqA[j] = f2bf((yq[j] * cs[j] + sgn * pA * sn[j]) * QSCL);
            outqB[j] = f2bf((yq[8 + j] * cs[j] + sgn * pB * sn[j]) * QSCL);
            float pkA = __shfl_xor(yk[j], 4, 64);
            float pkB = __shfl_xor(yk[8 + j], 4, 64);
            outkA[j] = f2bf(yk[j] * cs[j] + sgn * pkA * sn[j]);
            outkB[j] = f2bf(yk[8 + j] * cs[j] + sgn * pkB * sn[j]);
        }
        (void)pqA; (void)oqA1; (void)oqB0; (void)oqB1; (void)okA0; (void)okA1; (void)okB0; (void)okB1;
        // write: chunk A -> head hA = L>>3, dh0 = (L&7)*8 ; chunk B -> head 8+hA
        const int hA = L >> 3;
        const int dh0 = (L & 7) * 8;
        size_t offA = (((size_t)(b * Hh + hA)) * Ls + l) * DHh + dh0;
        size_t offB = (((size_t)(b * Hh + 8 + hA)) * Ls + l) * DHh + dh0;
        *(uint4*)(qt + offA) = *(uint4*)outqA;
        *(uint4*)(qt + offB) = *(uint4*)outqB;
        *(uint4*)(kt + offA) = *(uint4*)outkA;
        *(uint4*)(kt + offB) = *(uint4*)outkB;
    } else {
        // ---- V transpose tile ----
        const int t2 = blk - BL / 4;           // 0..1023
        const int l0 = (t2 & 31) * 64;
        const int h = (t2 >> 5) & 15;
        const int b = t2 >> 9;
        __shared__ short t[64][72];
        const unsigned short* src = qkvb + (size_t)b * Ls * (3 * Dd) + 2 * Dd + h * 64;
#pragma unroll
        for (int j = 0; j < 2; ++j) {
            int g = tid + j * 256;
            int row = g >> 3;
            int c0 = (g & 7) * 8;
            uint4 vv = *(const uint4*)(src + (size_t)(l0 + row) * (3 * Dd) + c0);
            *(uint4*)&t[row][c0] = vv;
        }
        __syncthreads();
        unsigned short* dst = vtt + ((size_t)(b * Hh + h) * DHh) * Ls;
#pragma unroll
        for (int j = 0; j < 2; ++j) {
            int g = tid + j * 256;
            int dh = g >> 3;
            int lc = (g & 7) * 8;
            ushort4 o0, o1;
            unsigned short* p0 = (unsigned short*)&o0;
            unsigned short* p1 = (unsigned short*)&o1;
#pragma unroll
            for (int i = 0; i < 4; ++i) p0[i] = (unsigned short)t[lc + i][dh];
#pragma unroll
            for (int i = 0; i < 4; ++i) p1[i] = (unsigned short)t[lc + 4 + i][dh];
            *(ushort4*)(dst + (size_t)dh * Ls + l0 + lc) = o0;
            *(ushort4*)(dst + (size_t)dh * Ls + l0 + lc + 4) = o1;
        }
    }
}

// ---------------- 5. MFMA flash attention (R11-proven) ------------------------
constexpr int PSP = 76;  // Ps pitch

__global__ __launch_bounds__(256) void attn_kernel(const unsigned short* __restrict__ qt,
                                                   const unsigned short* __restrict__ kt,
                                                   const unsigned short* __restrict__ vtt,
                                                   const int* __restrict__ seq_id,
                                                   unsigned short* __restrict__ ctxb) {
    const int id = blockIdx.x;            // 0..511
    const int c8 = id & 7;
    const int x = (id >> 3) & 15;
    const int g4 = id >> 7;
    const int v = c8 + 8 * g4;            // h + 16*b
    const int b = v >> 4;
    const int h = v & 15;
    const int q0 = x * 128;

    const size_t base = ((size_t)(b * Hh + h)) * Ls * DHh;
    const size_t base_v = ((size_t)(b * Hh + h)) * DHh * Ls;
    const int* sid = seq_id + (size_t)b * Ls;

    __shared__ short Ks[64 * 64];
    __shared__ short Vs[64 * 64];
    __shared__ short Ps[8][16 * PSP];
    __shared__ int sq_s[128];

    const int tid = threadIdx.x;
    const int w = tid >> 6;
    const int lane = tid & 63;
    const int quad = lane >> 4;
    const int l15 = lane & 15;

    if (tid < 128) sq_s[tid] = sid[q0 + tid];
    const int qmin = sid[q0];
    const int qmax = sid[q0 + 127];

    bf16x8 a0[2], a1[2];
#pragma unroll
    for (int sub = 0; sub < 2; ++sub) {
        int qrow = q0 + sub * 64 + w * 16 + l15;
        a0[sub] = *(const bf16x8*)(qt + base + (size_t)qrow * DHh + quad * 8);
        a1[sub] = *(const bf16x8*)(qt + base + (size_t)qrow * DHh + 32 + quad * 8);
    }

    bool need = false;
    if (lane < 32) {
        int kmn = sid[lane * 64];
        int kmx = sid[lane * 64 + 63];
        need = (kmn <= qmax) && (kmx >= qmin);
    }
    unsigned long long bmask = __ballot(need);
    const int t0 = __builtin_ctzll(bmask);
    const int t1 = 64 - __builtin_clzll(bmask);

    float lsum[2][4] = {{0.f, 0.f, 0.f, 0.f}, {0.f, 0.f, 0.f, 0.f}};
    f32x4 O[2][4];
#pragma unroll
    for (int sub = 0; sub < 2; ++sub)
#pragma unroll
        for (int r = 0; r < 4; ++r) O[sub][r] = f32x4{0.f, 0.f, 0.f, 0.f};

    for (int t = t0; t < t1; ++t) {
        const int k0 = t * 64;
        __syncthreads();
#pragma unroll
        for (int j = 0; j < 2; ++j) {
            int cc = tid + j * 256;
            int row = cc >> 3;
            int jg = (cc & 7) ^ (row & 7);
            async_copy16(kt + base + (size_t)(k0 + row) * DHh + jg * 8, &Ks[cc * 8]);
            async_copy16(vtt + base_v + (size_t)row * Ls + k0 + jg * 8, &Vs[cc * 8]);
        }
        __syncthreads();

        f32x4 s[2][4];
#pragma unroll
        for (int kg = 0; kg < 4; ++kg) {
            int krow = kg * 16 + l15;
            bf16x8 b0 = *(const bf16x8*)&Ks[krow * 64 + ((0 + quad) ^ (krow & 7)) * 8];
            bf16x8 b1 = *(const bf16x8*)&Ks[krow * 64 + ((4 + quad) ^ (krow & 7)) * 8];
#pragma unroll
            for (int sub = 0; sub < 2; ++sub) {
                f32x4 acc = {0.f, 0.f, 0.f, 0.f};
                acc = __builtin_amdgcn_mfma_f32_16x16x32_bf16(a0[sub], b0, acc, 0, 0, 0);
                acc = __builtin_amdgcn_mfma_f32_16x16x32_bf16(a1[sub], b1, acc, 0, 0, 0);
                s[sub][kg] = acc;
            }
        }
        const int kmn = sid[k0];
        const int kmx = sid[k0 + 63];
        const bool nomask = (kmn == kmx) && (qmin == qmax) && (kmn == qmin);
        if (!nomask) {
#pragma unroll
            for (int sub = 0; sub < 2; ++sub) {
                int sqv[4];
#pragma unroll
                for (int r = 0; r < 4; ++r) sqv[r] = sq_s[sub * 64 + w * 16 + quad * 4 + r];
#pragma unroll
                for (int kg = 0; kg < 4; ++kg) {
                    int skv = sid[k0 + kg * 16 + l15];
#pragma unroll
                    for (int r = 0; r < 4; ++r)
                        if (sqv[r] != skv) s[sub][kg][r] = -3.0e38f;
                }
            }
        }
#pragma unroll
        for (int sub = 0; sub < 2; ++sub) {
#pragma unroll
            for (int kg = 0; kg < 4; ++kg)
#pragma unroll
                for (int r = 0; r < 4; ++r)
                    s[sub][kg][r] = __builtin_amdgcn_exp2f(s[sub][kg][r]);
#pragma unroll
            for (int r = 0; r < 4; ++r)
                lsum[sub][r] += s[sub][0][r] + s[sub][1][r] + s[sub][2][r] + s[sub][3][r];
#pragma unroll
            for (int kg = 0; kg < 4; ++kg)
#pragma unroll
                for (int r = 0; r < 4; ++r)
                    Ps[w * 2 + sub][(quad * 4 + r) * PSP + kg * 16 + l15] =
                        (short)f2bf(s[sub][kg][r]);
        }
        bf16x8 pa0[2], pa1[2];
#pragma unroll
        for (int sub = 0; sub < 2; ++sub) {
            pa0[sub] = *(const bf16x8*)&Ps[w * 2 + sub][l15 * PSP + quad * 8];
            pa1[sub] = *(const bf16x8*)&Ps[w * 2 + sub][l15 * PSP + 32 + quad * 8];
        }
#pragma unroll
        for (int ng = 0; ng < 4; ++ng) {
            int vrow = ng * 16 + l15;
            bf16x8 vb0 = *(const bf16x8*)&Vs[vrow * 64 + ((0 + quad) ^ (vrow & 7)) * 8];
            bf16x8 vb1 = *(const bf16x8*)&Vs[vrow * 64 + ((4 + quad) ^ (vrow & 7)) * 8];
#pragma unroll
            for (int sub = 0; sub < 2; ++sub) {
                O[sub][ng] = __builtin_amdgcn_mfma_f32_16x16x32_bf16(pa0[sub], vb0, O[sub][ng], 0, 0, 0);
                O[sub][ng] = __builtin_amdgcn_mfma_f32_16x16x32_bf16(pa1[sub], vb1, O[sub][ng], 0, 0, 0);
            }
        }
    }

#pragma unroll
    for (int sub = 0; sub < 2; ++sub) {
#pragma unroll
        for (int off = 1; off < 16; off <<= 1)
#pragma unroll
            for (int r = 0; r < 4; ++r)
                lsum[sub][r] += __shfl_xor(lsum[sub][r], off, 64);
        float inv_l[4];
#pragma unroll
        for (int r = 0; r < 4; ++r) inv_l[r] = 1.0f / lsum[sub][r];
#pragma unroll
        for (int ng = 0; ng < 4; ++ng)
#pragma unroll
            for (int r = 0; r < 4; ++r) {
                int q = q0 + sub * 64 + w * 16 + quad * 4 + r;
                ctxb[((size_t)b * Ls + q) * Dd + h * DHh + ng * 16 + l15] =
                    f2bf(O[sub][ng][r] * inv_l[r]);
            }
    }
}

// ---------------- launcher ----------------
extern "C" void kernel_launch(void* const* d_in, const int* in_sizes, int n_in,
                              void* d_out, int out_size, void* d_ws, size_t ws_size,
                              hipStream_t stream) {
    const float* x = (const float*)d_in[0];
    const int* seq_id = (const int*)d_in[1];
    const float* ln_w = (const float*)d_in[2];
    const float* ln_b = (const float*)d_in[3];
    const float* w_qkv = (const float*)d_in[4];
    const float* q_lora_a = (const float*)d_in[5];
    const float* q_lora_b = (const float*)d_in[6];
    const float* v_lora_a = (const float*)d_in[7];
    const float* v_lora_b = (const float*)d_in[8];
    const float* q_ln_w = (const float*)d_in[9];
    const float* k_ln_w = (const float*)d_in[10];
    const float* w_out = (const float*)d_in[11];
    float* out = (float*)d_out;

    const size_t SZ = (size_t)BL * Dd;        // 4M elements
    float* p = (float*)d_ws;
    float* ropec = p;          p += (size_t)Ls * 32;
    float* ropes = p;          p += (size_t)Ls * 32;
    unsigned short* ub = (unsigned short*)p;
    unsigned short* qkvb = ub; ub += 3 * SZ;  // bf16 [BL, 3D]
    unsigned short* hb = ub;   ub += SZ;      // bf16 [BL, D]
    unsigned short* qt = ub;   ub += SZ;      // bf16 [B,H,L,DH] (prescaled)
    unsigned short* kt = ub;   ub += SZ;
    unsigned short* vtt = ub;  ub += SZ;      // bf16 [B,H,DH,L]
    unsigned short* ctxb = ub; ub += SZ;      // bf16 [BL, D]
    unsigned short* wqkvb = ub; ub += (size_t)3 * Dd * Dd;
    unsigned short* woutb = ub; ub += (size_t)Dd * Dd;

    prep_ln_kernel<<<4 * Dd + 256 + BL / 4, 256, 0, stream>>>(
        w_qkv, q_lora_a, q_lora_b, v_lora_a, v_lora_b, w_out,
        x, ln_w, ln_b, wqkvb, woutb, ropec, ropes, hb);
    {
        dim3 g(3 * Dd / 128, BL / 128);
        gemm_bt_mfma<<<g, 256, 0, stream>>>(hb, wqkvb, qkvb, BL, 3 * Dd, Dd);
    }
    qkv_final_kernel<<<BL / 4 + 1024, 256, 0, stream>>>(qkvb, q_ln_w, k_ln_w,
                                                        ropec, ropes, qt, kt, vtt);
    attn_kernel<<<512, 256, 0, stream>>>(qt, kt, vtt, seq_id, ctxb);
    {
        dim3 g(Dd / 64, BL / 128);
        gemm_bt_mfma_n64<<<g, 256, 0, stream>>>(ctxb, woutb, out, BL, Dd, Dd);
    }
}